// Round 1
// baseline (4884.011 us; speedup 1.0000x reference)
//
#include <hip/hip_runtime.h>

#define NN 100000
#define NE 1600000
#define CIN 64
#define CH 128
#define NCLS 8
#define NG 1000

// ---------------- index width detection + conversion ----------------
// If the harness delivered int64 indices, the int32 view has zero high words
// at odd positions. Random src values in [0,100000) make "all 128 odd slots
// zero" impossible for int32 data.
__global__ void k_detect(const void* __restrict__ edge, int* __restrict__ flag) {
    const int* e32 = (const int*)edge;
    int t = threadIdx.x;              // 128 threads
    int v = e32[2 * t + 1];
    unsigned long long any = __ballot(v != 0);
    if (t == 0) flag[0] = (any == 0ull) ? 1 : 0;
}

__global__ void k_convert(const void* __restrict__ edge, const void* __restrict__ batch,
                          const int* __restrict__ flag,
                          int* __restrict__ srci, int* __restrict__ dsti, int* __restrict__ bati) {
    const int total = 2 * NE + NN;
    const int idx0 = blockIdx.x * blockDim.x + threadIdx.x;
    const int stride = gridDim.x * blockDim.x;
    if (flag[0] != 0) {
        const long long* e64 = (const long long*)edge;
        const long long* b64 = (const long long*)batch;
        for (int i = idx0; i < total; i += stride) {
            int v = (i < 2 * NE) ? (int)e64[i] : (int)b64[i - 2 * NE];
            if (i < NE) srci[i] = v;
            else if (i < 2 * NE) dsti[i - NE] = v;
            else bati[i - 2 * NE] = v;
        }
    } else {
        const int* e32 = (const int*)edge;
        const int* b32 = (const int*)batch;
        for (int i = idx0; i < total; i += stride) {
            int v = (i < 2 * NE) ? e32[i] : b32[i - 2 * NE];
            if (i < NE) srci[i] = v;
            else if (i < 2 * NE) dsti[i - NE] = v;
            else bati[i - 2 * NE] = v;
        }
    }
}

// ---------------- degree ----------------
__global__ __launch_bounds__(256) void k_deg(const int* __restrict__ dst, float* __restrict__ cnt) {
    for (int e = blockIdx.x * blockDim.x + threadIdx.x; e < NE; e += gridDim.x * blockDim.x)
        atomicAdd(&cnt[dst[e]], 1.0f);
}

// ---------------- scatter-add of features over edges ----------------
template <int C>
__global__ __launch_bounds__(256) void k_scatter(const int* __restrict__ src, const int* __restrict__ dst,
                                                 const float* __restrict__ feat, float* __restrict__ msg) {
    constexpr int G = C / 4;                 // float4 groups per row (16 or 32)
    constexpr int SH = (C == 64) ? 4 : 5;    // log2(G)
    const int total = NE * G;
    for (int idx = blockIdx.x * blockDim.x + threadIdx.x; idx < total; idx += gridDim.x * blockDim.x) {
        const int e = idx >> SH;
        const int g = idx & (G - 1);
        const int s = src[e];
        const int d = dst[e];
        float4 v = *(const float4*)&feat[(size_t)s * C + 4 * g];
        float* p = &msg[(size_t)d * C + 4 * g];
        atomicAdd(p + 0, v.x);
        atomicAdd(p + 1, v.y);
        atomicAdd(p + 2, v.z);
        atomicAdd(p + 3, v.w);
    }
}

// ---------------- layer 1 fused: h = relu(mean @ Wl + x @ Wr + b) ----------------
__global__ __launch_bounds__(128) void k_sage1(const float* __restrict__ x, const float* __restrict__ msg,
                                               const float* __restrict__ cnt,
                                               const float* __restrict__ Wl, const float* __restrict__ Wr,
                                               const float* __restrict__ b, float* __restrict__ h) {
    __shared__ float sWl[CIN * CH];
    __shared__ float sWr[CIN * CH];
    for (int t = threadIdx.x; t < CIN * CH / 4; t += blockDim.x) {
        ((float4*)sWl)[t] = ((const float4*)Wl)[t];
        ((float4*)sWr)[t] = ((const float4*)Wr)[t];
    }
    __syncthreads();
    const int j = threadIdx.x;
    const float bj = b[j];
    for (int i = blockIdx.x; i < NN; i += gridDim.x) {
        const float inv = 1.0f / fmaxf(cnt[i], 1.0f);
        const float4* xr = (const float4*)&x[(size_t)i * CIN];
        const float4* mr = (const float4*)&msg[(size_t)i * CIN];
        float accR = bj;   // x @ Wr + b
        float accL = 0.f;  // msg @ Wl (scaled by inv at the end)
#pragma unroll
        for (int k4 = 0; k4 < CIN / 4; k4++) {
            float4 xv = xr[k4];
            float4 mv = mr[k4];
            const int kb = k4 * 4 * CH + j;
            accR = fmaf(xv.x, sWr[kb], accR);          accL = fmaf(mv.x, sWl[kb], accL);
            accR = fmaf(xv.y, sWr[kb + CH], accR);     accL = fmaf(mv.y, sWl[kb + CH], accL);
            accR = fmaf(xv.z, sWr[kb + 2 * CH], accR); accL = fmaf(mv.z, sWl[kb + 2 * CH], accL);
            accR = fmaf(xv.w, sWr[kb + 3 * CH], accR); accL = fmaf(mv.w, sWl[kb + 3 * CH], accL);
        }
        h[(size_t)i * CH + j] = fmaxf(fmaf(inv, accL, accR), 0.0f);
    }
}

// ---------------- layer 2 pass A: msg <- (msg / cnt) @ W2_l  (in-place, row-wise) ----------------
__global__ __launch_bounds__(128) void k_l2a(float* __restrict__ msg, const float* __restrict__ cnt,
                                             const float* __restrict__ W) {
    __shared__ float sW[CH * CH];
    for (int t = threadIdx.x; t < CH * CH / 4; t += blockDim.x)
        ((float4*)sW)[t] = ((const float4*)W)[t];
    __syncthreads();
    const int j = threadIdx.x;
    for (int i = blockIdx.x; i < NN; i += gridDim.x) {
        const float inv = 1.0f / fmaxf(cnt[i], 1.0f);
        const float4* mr = (const float4*)&msg[(size_t)i * CH];
        float acc = 0.f;
#pragma unroll
        for (int k4 = 0; k4 < CH / 4; k4++) {
            float4 mv = mr[k4];
            const int kb = k4 * 4 * CH + j;
            acc = fmaf(mv.x, sW[kb], acc);
            acc = fmaf(mv.y, sW[kb + CH], acc);
            acc = fmaf(mv.z, sW[kb + 2 * CH], acc);
            acc = fmaf(mv.w, sW[kb + 3 * CH], acc);
        }
        acc *= inv;
        __syncthreads();                    // all reads of row i done before any write
        msg[(size_t)i * CH + j] = acc;
    }
}

// ---------------- layer 2 pass B: h <- relu(tmp + h @ W2_r + b)  (in-place, row-wise) ----------------
__global__ __launch_bounds__(128) void k_l2b(float* __restrict__ h, const float* __restrict__ tmp,
                                             const float* __restrict__ W, const float* __restrict__ b) {
    __shared__ float sW[CH * CH];
    for (int t = threadIdx.x; t < CH * CH / 4; t += blockDim.x)
        ((float4*)sW)[t] = ((const float4*)W)[t];
    __syncthreads();
    const int j = threadIdx.x;
    const float bj = b[j];
    for (int i = blockIdx.x; i < NN; i += gridDim.x) {
        const float4* hr = (const float4*)&h[(size_t)i * CH];
        float acc = bj + tmp[(size_t)i * CH + j];
#pragma unroll
        for (int k4 = 0; k4 < CH / 4; k4++) {
            float4 hv = hr[k4];
            const int kb = k4 * 4 * CH + j;
            acc = fmaf(hv.x, sW[kb], acc);
            acc = fmaf(hv.y, sW[kb + CH], acc);
            acc = fmaf(hv.z, sW[kb + 2 * CH], acc);
            acc = fmaf(hv.w, sW[kb + 3 * CH], acc);
        }
        __syncthreads();                    // all reads of row i done before any write
        h[(size_t)i * CH + j] = fmaxf(acc, 0.0f);
    }
}

// ---------------- fused global-mean-pool + head ----------------
__device__ __forceinline__ int lower_bound_dev(const int* __restrict__ a, int n, int key) {
    int lo = 0, hi = n;
    while (lo < hi) {
        int mid = (lo + hi) >> 1;
        if (a[mid] < key) lo = mid + 1; else hi = mid;
    }
    return lo;
}

__global__ __launch_bounds__(128) void k_pool(const float* __restrict__ h, const int* __restrict__ batch,
                                              const float* __restrict__ Wh, const float* __restrict__ bh,
                                              float* __restrict__ out) {
    const int g = blockIdx.x;
    const int lo = lower_bound_dev(batch, NN, g);
    const int hi = lower_bound_dev(batch, NN, g + 1);
    const int j = threadIdx.x;
    float s = 0.f;
    for (int i = lo; i < hi; i++) s += h[(size_t)i * CH + j];
    __shared__ float pooled[CH];
    pooled[j] = s / fmaxf((float)(hi - lo), 1.0f);
    __syncthreads();
    if (j < NCLS) {
        float acc = bh[j];
#pragma unroll
        for (int k = 0; k < CH; k++) acc = fmaf(pooled[k], Wh[k * NCLS + j], acc);
        out[(size_t)g * NCLS + j] = acc;
    }
}

extern "C" void kernel_launch(void* const* d_in, const int* in_sizes, int n_in,
                              void* d_out, int out_size, void* d_ws, size_t ws_size,
                              hipStream_t stream) {
    const float* x   = (const float*)d_in[0];
    const void* edge = d_in[1];
    const void* batch= d_in[2];
    const float* W1l = (const float*)d_in[3];
    const float* W1r = (const float*)d_in[4];
    const float* b1  = (const float*)d_in[5];
    const float* W2l = (const float*)d_in[6];
    const float* W2r = (const float*)d_in[7];
    const float* b2  = (const float*)d_in[8];
    const float* Wh  = (const float*)d_in[9];
    const float* bh  = (const float*)d_in[10];
    float* out = (float*)d_out;

    char* p = (char*)d_ws;
    float* msg = (float*)p;  p += (size_t)NN * CH * sizeof(float);   // 51.2 MB
    float* h   = (float*)p;  p += (size_t)NN * CH * sizeof(float);   // 51.2 MB
    float* cnt = (float*)p;  p += (size_t)NN * sizeof(float);
    int* srci  = (int*)p;    p += (size_t)NE * sizeof(int);
    int* dsti  = (int*)p;    p += (size_t)NE * sizeof(int);
    int* bati  = (int*)p;    p += (size_t)NN * sizeof(int);
    int* flag  = (int*)p;    p += 256;

    k_detect<<<1, 128, 0, stream>>>(edge, flag);
    k_convert<<<2048, 256, 0, stream>>>(edge, batch, flag, srci, dsti, bati);

    hipMemsetAsync(cnt, 0, NN * sizeof(float), stream);
    hipMemsetAsync(msg, 0, (size_t)NN * CIN * sizeof(float), stream);
    k_deg<<<1024, 256, 0, stream>>>(dsti, cnt);
    k_scatter<CIN><<<4096, 256, 0, stream>>>(srci, dsti, x, msg);
    k_sage1<<<1024, 128, 0, stream>>>(x, msg, cnt, W1l, W1r, b1, h);

    hipMemsetAsync(msg, 0, (size_t)NN * CH * sizeof(float), stream);
    k_scatter<CH><<<8192, 256, 0, stream>>>(srci, dsti, h, msg);
    k_l2a<<<1024, 128, 0, stream>>>(msg, cnt, W2l);
    k_l2b<<<1024, 128, 0, stream>>>(h, msg, W2r, b2);

    k_pool<<<NG, 128, 0, stream>>>(h, bati, Wh, bh, out);
}

// Round 2
// 1386.292 us; speedup vs baseline: 3.5231x; 3.5231x over previous
//
#include <hip/hip_runtime.h>

#define NN 100000
#define NE 1600000
#define CIN 64
#define CH 128
#define NCLS 8
#define NG 1000

// ---------------- index width detection ----------------
// If indices are int64, the int32 view has all-zero high words at odd slots.
__global__ void k_detect(const void* __restrict__ edge, int* __restrict__ flag) {
    const int* e32 = (const int*)edge;
    int t = threadIdx.x;              // 128 threads
    int v = e32[2 * t + 1];
    unsigned long long any = __ballot(v != 0);
    if (t == 0) flag[0] = (any == 0ull) ? 1 : 0;
}

__global__ void k_cvtbatch(const void* __restrict__ batch, const int* __restrict__ flag,
                           int* __restrict__ bati) {
    int i = blockIdx.x * blockDim.x + threadIdx.x;
    if (i >= NN) return;
    bati[i] = flag[0] ? (int)((const long long*)batch)[i] : ((const int*)batch)[i];
}

// ---------------- degree (int) ----------------
__global__ __launch_bounds__(256) void k_deg(const void* __restrict__ edge, const int* __restrict__ flag,
                                             int* __restrict__ deg) {
    const bool w64 = flag[0] != 0;
    const int idx0 = blockIdx.x * blockDim.x + threadIdx.x;
    const int stride = gridDim.x * blockDim.x;
    if (w64) {
        const long long* d = (const long long*)edge + NE;
        for (int e = idx0; e < NE; e += stride) atomicAdd(&deg[(int)d[e]], 1);
    } else {
        const int* d = (const int*)edge + NE;
        for (int e = idx0; e < NE; e += stride) atomicAdd(&deg[d[e]], 1);
    }
}

// ---------------- exclusive scan of deg -> rowstart (single block) ----------------
__global__ __launch_bounds__(1024) void k_scan(const int* __restrict__ deg, int* __restrict__ rowstart) {
    __shared__ int buf[1024];
    __shared__ int carry;
    if (threadIdx.x == 0) carry = 0;
    __syncthreads();
    for (int base = 0; base < NN; base += 1024) {
        int i = base + threadIdx.x;
        int v = (i < NN) ? deg[i] : 0;
        buf[threadIdx.x] = v;
        __syncthreads();
        for (int off = 1; off < 1024; off <<= 1) {
            int t = (threadIdx.x >= off) ? buf[threadIdx.x - off] : 0;
            __syncthreads();
            buf[threadIdx.x] += t;
            __syncthreads();
        }
        if (i < NN) rowstart[i] = carry + buf[threadIdx.x] - v;
        __syncthreads();
        if (threadIdx.x == 0) carry += buf[1023];
        __syncthreads();
    }
    if (threadIdx.x == 0) rowstart[NN] = carry;   // == NE
}

// ---------------- CSR fill: eidx[cursor[dst]++] = src ----------------
__global__ __launch_bounds__(256) void k_fill(const void* __restrict__ edge, const int* __restrict__ flag,
                                              int* __restrict__ cursor, int* __restrict__ eidx) {
    const bool w64 = flag[0] != 0;
    const int idx0 = blockIdx.x * blockDim.x + threadIdx.x;
    const int stride = gridDim.x * blockDim.x;
    if (w64) {
        const long long* e = (const long long*)edge;
        for (int i = idx0; i < NE; i += stride) {
            int s = (int)e[i];
            int d = (int)e[NE + i];
            int pos = atomicAdd(&cursor[d], 1);
            eidx[pos] = s;
        }
    } else {
        const int* e = (const int*)edge;
        for (int i = idx0; i < NE; i += stride) {
            int s = e[i];
            int d = e[NE + i];
            int pos = atomicAdd(&cursor[d], 1);
            eidx[pos] = s;
        }
    }
}

// ---------------- gather-mean: msg[i] = mean over in-edges of feat[src] ----------------
// One wave (64 lanes) per node. C=64: lane=channel; C=128: lane handles float2.
template <int C>
__global__ __launch_bounds__(256) void k_gather(const float* __restrict__ feat,
                                                const int* __restrict__ eidx,
                                                const int* __restrict__ rowstart,
                                                float* __restrict__ msg) {
    const int node = blockIdx.x * 4 + (threadIdx.x >> 6);
    if (node >= NN) return;
    const int lane = threadIdx.x & 63;
    const int lo = rowstart[node];
    const int hi = rowstart[node + 1];
    if (C == 64) {
        float acc = 0.f;
        for (int e = lo; e < hi; e++) {
            int s = eidx[e];
            acc += feat[(size_t)s * 64 + lane];
        }
        msg[(size_t)node * 64 + lane] = acc * (1.0f / fmaxf((float)(hi - lo), 1.0f));
    } else {
        float2 acc = make_float2(0.f, 0.f);
        for (int e = lo; e < hi; e++) {
            int s = eidx[e];
            float2 v = *(const float2*)&feat[(size_t)s * 128 + lane * 2];
            acc.x += v.x; acc.y += v.y;
        }
        float inv = 1.0f / fmaxf((float)(hi - lo), 1.0f);
        acc.x *= inv; acc.y *= inv;
        *(float2*)&msg[(size_t)node * 128 + lane * 2] = acc;
    }
}

// ---------------- layer 1 fused: h = relu(mean @ Wl + x @ Wr + b) ----------------
__global__ __launch_bounds__(128) void k_sage1(const float* __restrict__ x, const float* __restrict__ msg,
                                               const float* __restrict__ Wl, const float* __restrict__ Wr,
                                               const float* __restrict__ b, float* __restrict__ h) {
    __shared__ float sWl[CIN * CH];
    __shared__ float sWr[CIN * CH];
    for (int t = threadIdx.x; t < CIN * CH / 4; t += blockDim.x) {
        ((float4*)sWl)[t] = ((const float4*)Wl)[t];
        ((float4*)sWr)[t] = ((const float4*)Wr)[t];
    }
    __syncthreads();
    const int j = threadIdx.x;
    const float bj = b[j];
    for (int i = blockIdx.x; i < NN; i += gridDim.x) {
        const float4* xr = (const float4*)&x[(size_t)i * CIN];
        const float4* mr = (const float4*)&msg[(size_t)i * CIN];
        float accR = bj;   // x @ Wr + b
        float accL = 0.f;  // mean @ Wl
#pragma unroll
        for (int k4 = 0; k4 < CIN / 4; k4++) {
            float4 xv = xr[k4];
            float4 mv = mr[k4];
            const int kb = k4 * 4 * CH + j;
            accR = fmaf(xv.x, sWr[kb], accR);          accL = fmaf(mv.x, sWl[kb], accL);
            accR = fmaf(xv.y, sWr[kb + CH], accR);     accL = fmaf(mv.y, sWl[kb + CH], accL);
            accR = fmaf(xv.z, sWr[kb + 2 * CH], accR); accL = fmaf(mv.z, sWl[kb + 2 * CH], accL);
            accR = fmaf(xv.w, sWr[kb + 3 * CH], accR); accL = fmaf(mv.w, sWl[kb + 3 * CH], accL);
        }
        h[(size_t)i * CH + j] = fmaxf(accL + accR, 0.0f);
    }
}

// ---------------- layer 2 pass A: msg <- msg @ W2_l (in-place; msg is already mean) ---------
__global__ __launch_bounds__(128) void k_l2a(float* __restrict__ msg, const float* __restrict__ W) {
    __shared__ float sW[CH * CH];
    for (int t = threadIdx.x; t < CH * CH / 4; t += blockDim.x)
        ((float4*)sW)[t] = ((const float4*)W)[t];
    __syncthreads();
    const int j = threadIdx.x;
    for (int i = blockIdx.x; i < NN; i += gridDim.x) {
        const float4* mr = (const float4*)&msg[(size_t)i * CH];
        float acc = 0.f;
#pragma unroll
        for (int k4 = 0; k4 < CH / 4; k4++) {
            float4 mv = mr[k4];
            const int kb = k4 * 4 * CH + j;
            acc = fmaf(mv.x, sW[kb], acc);
            acc = fmaf(mv.y, sW[kb + CH], acc);
            acc = fmaf(mv.z, sW[kb + 2 * CH], acc);
            acc = fmaf(mv.w, sW[kb + 3 * CH], acc);
        }
        __syncthreads();                    // all reads of row i done before any write
        msg[(size_t)i * CH + j] = acc;
    }
}

// ---------------- layer 2 pass B: h <- relu(tmp + h @ W2_r + b) (in-place) ----------------
__global__ __launch_bounds__(128) void k_l2b(float* __restrict__ h, const float* __restrict__ tmp,
                                             const float* __restrict__ W, const float* __restrict__ b) {
    __shared__ float sW[CH * CH];
    for (int t = threadIdx.x; t < CH * CH / 4; t += blockDim.x)
        ((float4*)sW)[t] = ((const float4*)W)[t];
    __syncthreads();
    const int j = threadIdx.x;
    const float bj = b[j];
    for (int i = blockIdx.x; i < NN; i += gridDim.x) {
        const float4* hr = (const float4*)&h[(size_t)i * CH];
        float acc = bj + tmp[(size_t)i * CH + j];
#pragma unroll
        for (int k4 = 0; k4 < CH / 4; k4++) {
            float4 hv = hr[k4];
            const int kb = k4 * 4 * CH + j;
            acc = fmaf(hv.x, sW[kb], acc);
            acc = fmaf(hv.y, sW[kb + CH], acc);
            acc = fmaf(hv.z, sW[kb + 2 * CH], acc);
            acc = fmaf(hv.w, sW[kb + 3 * CH], acc);
        }
        __syncthreads();                    // all reads of row i done before any write
        h[(size_t)i * CH + j] = fmaxf(acc, 0.0f);
    }
}

// ---------------- fused global-mean-pool + head ----------------
__device__ __forceinline__ int lower_bound_dev(const int* __restrict__ a, int n, int key) {
    int lo = 0, hi = n;
    while (lo < hi) {
        int mid = (lo + hi) >> 1;
        if (a[mid] < key) lo = mid + 1; else hi = mid;
    }
    return lo;
}

__global__ __launch_bounds__(128) void k_pool(const float* __restrict__ h, const int* __restrict__ batch,
                                              const float* __restrict__ Wh, const float* __restrict__ bh,
                                              float* __restrict__ out) {
    const int g = blockIdx.x;
    const int lo = lower_bound_dev(batch, NN, g);
    const int hi = lower_bound_dev(batch, NN, g + 1);
    const int j = threadIdx.x;
    float s = 0.f;
    for (int i = lo; i < hi; i++) s += h[(size_t)i * CH + j];
    __shared__ float pooled[CH];
    pooled[j] = s / fmaxf((float)(hi - lo), 1.0f);
    __syncthreads();
    if (j < NCLS) {
        float acc = bh[j];
#pragma unroll
        for (int k = 0; k < CH; k++) acc = fmaf(pooled[k], Wh[k * NCLS + j], acc);
        out[(size_t)g * NCLS + j] = acc;
    }
}

extern "C" void kernel_launch(void* const* d_in, const int* in_sizes, int n_in,
                              void* d_out, int out_size, void* d_ws, size_t ws_size,
                              hipStream_t stream) {
    const float* x   = (const float*)d_in[0];
    const void* edge = d_in[1];
    const void* batch= d_in[2];
    const float* W1l = (const float*)d_in[3];
    const float* W1r = (const float*)d_in[4];
    const float* b1  = (const float*)d_in[5];
    const float* W2l = (const float*)d_in[6];
    const float* W2r = (const float*)d_in[7];
    const float* b2  = (const float*)d_in[8];
    const float* Wh  = (const float*)d_in[9];
    const float* bh  = (const float*)d_in[10];
    float* out = (float*)d_out;

    char* p = (char*)d_ws;
    float* msg = (float*)p;     p += (size_t)NN * CH * sizeof(float);   // 51.2 MB
    float* h   = (float*)p;     p += (size_t)NN * CH * sizeof(float);   // 51.2 MB
    int* bati  = (int*)p;       p += (size_t)NN * sizeof(int);
    int* deg   = (int*)p;       p += (size_t)NN * sizeof(int);
    int* rowstart = (int*)p;    p += (size_t)(NN + 1) * sizeof(int);
    int* cursor   = (int*)p;    p += (size_t)(NN + 1) * sizeof(int);
    int* eidx  = (int*)p;       p += (size_t)NE * sizeof(int);          // 6.4 MB
    int* flag  = (int*)p;       p += 256;

    k_detect<<<1, 128, 0, stream>>>(edge, flag);
    k_cvtbatch<<<(NN + 255) / 256, 256, 0, stream>>>(batch, flag, bati);

    hipMemsetAsync(deg, 0, NN * sizeof(int), stream);
    k_deg<<<1024, 256, 0, stream>>>(edge, flag, deg);
    k_scan<<<1, 1024, 0, stream>>>(deg, rowstart);
    hipMemcpyAsync(cursor, rowstart, NN * sizeof(int), hipMemcpyDeviceToDevice, stream);
    k_fill<<<4096, 256, 0, stream>>>(edge, flag, cursor, eidx);

    k_gather<CIN><<<(NN + 3) / 4, 256, 0, stream>>>(x, eidx, rowstart, msg);
    k_sage1<<<1024, 128, 0, stream>>>(x, msg, W1l, W1r, b1, h);

    k_gather<CH><<<(NN + 3) / 4, 256, 0, stream>>>(h, eidx, rowstart, msg);
    k_l2a<<<1024, 128, 0, stream>>>(msg, W2l);
    k_l2b<<<1024, 128, 0, stream>>>(h, msg, W2r, b2);

    k_pool<<<NG, 128, 0, stream>>>(h, bati, Wh, bh, out);
}

// Round 3
// 769.378 us; speedup vs baseline: 6.3480x; 1.8018x over previous
//
#include <hip/hip_runtime.h>

#define NN 100000
#define NE 1600000
#define CIN 64
#define CH 128
#define NCLS 8
#define NG 1000

typedef __attribute__((ext_vector_type(8))) short bf16x8;
typedef __attribute__((ext_vector_type(8))) unsigned short ushort8;
typedef __attribute__((ext_vector_type(4))) float f32x4;

__device__ __forceinline__ float bf2f(unsigned short u) {
    union { unsigned int i; float f; } c; c.i = ((unsigned int)u) << 16; return c.f;
}
__device__ __forceinline__ unsigned short f2bf(float f) {
    union { float f; unsigned int i; } c; c.f = f;
    unsigned int r = c.i + 0x7FFFu + ((c.i >> 16) & 1u);
    return (unsigned short)(r >> 16);
}

// ---------------- index width detection ----------------
__global__ void k_detect(const void* __restrict__ edge, int* __restrict__ flag) {
    const int* e32 = (const int*)edge;
    int t = threadIdx.x;              // 128 threads
    int v = e32[2 * t + 1];
    unsigned long long any = __ballot(v != 0);
    if (t == 0) flag[0] = (any == 0ull) ? 1 : 0;
}

__global__ void k_cvtbatch(const void* __restrict__ batch, const int* __restrict__ flag,
                           int* __restrict__ bati) {
    int i = blockIdx.x * blockDim.x + threadIdx.x;
    if (i >= NN) return;
    bati[i] = flag[0] ? (int)((const long long*)batch)[i] : ((const int*)batch)[i];
}

// ---------------- degree ----------------
__global__ __launch_bounds__(256) void k_deg(const void* __restrict__ edge, const int* __restrict__ flag,
                                             int* __restrict__ deg) {
    const bool w64 = flag[0] != 0;
    const int idx0 = blockIdx.x * blockDim.x + threadIdx.x;
    const int stride = gridDim.x * blockDim.x;
    if (w64) {
        const long long* d = (const long long*)edge + NE;
        for (int e = idx0; e < NE; e += stride) atomicAdd(&deg[(int)d[e]], 1);
    } else {
        const int* d = (const int*)edge + NE;
        for (int e = idx0; e < NE; e += stride) atomicAdd(&deg[d[e]], 1);
    }
}

// ---------------- exclusive scan of deg -> rowstart (single block) ----------------
__global__ __launch_bounds__(1024) void k_scan(const int* __restrict__ deg, int* __restrict__ rowstart) {
    __shared__ int buf[1024];
    __shared__ int carry;
    if (threadIdx.x == 0) carry = 0;
    __syncthreads();
    for (int base = 0; base < NN; base += 1024) {
        int i = base + threadIdx.x;
        int v = (i < NN) ? deg[i] : 0;
        buf[threadIdx.x] = v;
        __syncthreads();
        for (int off = 1; off < 1024; off <<= 1) {
            int t = (threadIdx.x >= off) ? buf[threadIdx.x - off] : 0;
            __syncthreads();
            buf[threadIdx.x] += t;
            __syncthreads();
        }
        if (i < NN) rowstart[i] = carry + buf[threadIdx.x] - v;
        __syncthreads();
        if (threadIdx.x == 0) carry += buf[1023];
        __syncthreads();
    }
    if (threadIdx.x == 0) rowstart[NN] = carry;   // == NE
}

// ---------------- CSR fill ----------------
__global__ __launch_bounds__(256) void k_fill(const void* __restrict__ edge, const int* __restrict__ flag,
                                              int* __restrict__ cursor, int* __restrict__ eidx) {
    const bool w64 = flag[0] != 0;
    const int idx0 = blockIdx.x * blockDim.x + threadIdx.x;
    const int stride = gridDim.x * blockDim.x;
    if (w64) {
        const long long* e = (const long long*)edge;
        for (int i = idx0; i < NE; i += stride) {
            int s = (int)e[i];
            int d = (int)e[NE + i];
            int pos = atomicAdd(&cursor[d], 1);
            eidx[pos] = s;
        }
    } else {
        const int* e = (const int*)edge;
        for (int i = idx0; i < NE; i += stride) {
            int s = e[i];
            int d = e[NE + i];
            int pos = atomicAdd(&cursor[d], 1);
            eidx[pos] = s;
        }
    }
}

// ---------------- fp32 -> bf16 feature conversion ----------------
__global__ void k_cvtx(const float* __restrict__ x, unsigned short* __restrict__ xb, int total8) {
    int i = blockIdx.x * blockDim.x + threadIdx.x;
    if (i >= total8) return;
    float4 v0 = ((const float4*)x)[2 * i];
    float4 v1 = ((const float4*)x)[2 * i + 1];
    ushort8 o;
    o[0] = f2bf(v0.x); o[1] = f2bf(v0.y); o[2] = f2bf(v0.z); o[3] = f2bf(v0.w);
    o[4] = f2bf(v1.x); o[5] = f2bf(v1.y); o[6] = f2bf(v1.z); o[7] = f2bf(v1.w);
    ((ushort8*)xb)[i] = o;
}

// ---------------- weight -> fragment-ready bf16 layout ----------------
// W is [K][N] row-major fp32. Output: frag (nt, ks, lane) -> 8 bf16:
//   out[((nt*(K/32)+ks)*64+l)*8 + j] = bf16(W[ks*32 + (l>>4)*8 + j][nt*16 + (l&15)])
__global__ void k_cvtW(const float* __restrict__ W, int K, int N, unsigned short* __restrict__ out) {
    int idx = blockIdx.x * blockDim.x + threadIdx.x;
    int total = (N / 16) * (K / 32) * 64;
    if (idx >= total) return;
    int l = idx & 63;
    int ks = (idx >> 6) % (K / 32);
    int nt = (idx >> 6) / (K / 32);
    int krow = ks * 32 + (l >> 4) * 8;
    int col = nt * 16 + (l & 15);
    ushort8 o;
#pragma unroll
    for (int j = 0; j < 8; j++) o[j] = f2bf(W[(size_t)(krow + j) * N + col]);
    ((ushort8*)out)[idx] = o;
}

// ---------------- gather-mean over in-edges (bf16 features, fp32 accum) ----------------
template <int C>
__global__ __launch_bounds__(256) void k_gatherb(const unsigned short* __restrict__ feat,
                                                 const int* __restrict__ eidx,
                                                 const int* __restrict__ rowstart,
                                                 unsigned short* __restrict__ msg) {
    const int node = blockIdx.x * 4 + (threadIdx.x >> 6);
    if (node >= NN) return;
    const int lane = threadIdx.x & 63;
    const int lo = rowstart[node];
    const int hi = rowstart[node + 1];
    if (C == 64) {
        float acc = 0.f;
        for (int e = lo; e < hi; e++) {
            int s = eidx[e];
            acc += bf2f(feat[(size_t)s * 64 + lane]);
        }
        msg[(size_t)node * 64 + lane] = f2bf(acc / fmaxf((float)(hi - lo), 1.0f));
    } else {
        float a0 = 0.f, a1 = 0.f;
        for (int e = lo; e < hi; e++) {
            int s = eidx[e];
            ushort2 v = *(const ushort2*)&feat[(size_t)s * 128 + lane * 2];
            a0 += bf2f(v.x); a1 += bf2f(v.y);
        }
        float inv = 1.0f / fmaxf((float)(hi - lo), 1.0f);
        ushort2 o; o.x = f2bf(a0 * inv); o.y = f2bf(a1 * inv);
        *(ushort2*)&msg[(size_t)node * 128 + lane * 2] = o;
    }
}

// ---------------- fused SAGE layer via MFMA: out = relu(A1@B1 + A2@B2 + bias) ----------------
// A1,A2: [NN][K] bf16 row-major. B1,B2: fragment-ready (k_cvtW). out: [NN][128] bf16.
// Block = 256 thr (4 waves), each wave computes 16 rows x 128 cols.
template <int K>
__global__ __launch_bounds__(256) void k_sage_mfma(const unsigned short* __restrict__ A1,
                                                   const unsigned short* __restrict__ A2,
                                                   const unsigned short* __restrict__ B1,
                                                   const unsigned short* __restrict__ B2,
                                                   const float* __restrict__ bias,
                                                   unsigned short* __restrict__ out) {
    constexpr int KS = K / 32;
    const int wid = threadIdx.x >> 6;
    const int lane = threadIdx.x & 63;
    const int rowbase = blockIdx.x * 64 + wid * 16;
    const int arow = rowbase + (lane & 15);
    const int arowc = (arow < NN) ? arow : (NN - 1);
    const int kgrp = (lane >> 4) * 8;

    f32x4 acc[8];
#pragma unroll
    for (int nt = 0; nt < 8; nt++) {
        float bj = bias[nt * 16 + (lane & 15)];
        acc[nt][0] = bj; acc[nt][1] = bj; acc[nt][2] = bj; acc[nt][3] = bj;
    }

    const bf16x8* b1v = (const bf16x8*)B1;
    const bf16x8* b2v = (const bf16x8*)B2;
#pragma unroll
    for (int ks = 0; ks < KS; ks++) {
        bf16x8 a1 = *(const bf16x8*)&A1[(size_t)arowc * K + ks * 32 + kgrp];
        bf16x8 a2 = *(const bf16x8*)&A2[(size_t)arowc * K + ks * 32 + kgrp];
#pragma unroll
        for (int nt = 0; nt < 8; nt++) {
            acc[nt] = __builtin_amdgcn_mfma_f32_16x16x32_bf16(a1, b1v[(nt * KS + ks) * 64 + lane], acc[nt], 0, 0, 0);
            acc[nt] = __builtin_amdgcn_mfma_f32_16x16x32_bf16(a2, b2v[(nt * KS + ks) * 64 + lane], acc[nt], 0, 0, 0);
        }
    }

    const int colb = lane & 15;
    const int rhi = (lane >> 4) * 4;
#pragma unroll
    for (int nt = 0; nt < 8; nt++) {
#pragma unroll
        for (int r = 0; r < 4; r++) {
            int row = rowbase + rhi + r;
            if (row < NN)
                out[(size_t)row * 128 + nt * 16 + colb] = f2bf(fmaxf(acc[nt][r], 0.0f));
        }
    }
}

// ---------------- fused global-mean-pool + head (bf16 h, fp32 math) ----------------
__device__ __forceinline__ int lower_bound_dev(const int* __restrict__ a, int n, int key) {
    int lo = 0, hi = n;
    while (lo < hi) {
        int mid = (lo + hi) >> 1;
        if (a[mid] < key) lo = mid + 1; else hi = mid;
    }
    return lo;
}

__global__ __launch_bounds__(128) void k_poolb(const unsigned short* __restrict__ h,
                                               const int* __restrict__ batch,
                                               const float* __restrict__ Wh, const float* __restrict__ bh,
                                               float* __restrict__ out) {
    const int g = blockIdx.x;
    const int lo = lower_bound_dev(batch, NN, g);
    const int hi = lower_bound_dev(batch, NN, g + 1);
    const int j = threadIdx.x;
    float s = 0.f;
    for (int i = lo; i < hi; i++) s += bf2f(h[(size_t)i * CH + j]);
    __shared__ float pooled[CH];
    pooled[j] = s / fmaxf((float)(hi - lo), 1.0f);
    __syncthreads();
    if (j < NCLS) {
        float acc = bh[j];
#pragma unroll
        for (int k = 0; k < CH; k++) acc = fmaf(pooled[k], Wh[k * NCLS + j], acc);
        out[(size_t)g * NCLS + j] = acc;
    }
}

extern "C" void kernel_launch(void* const* d_in, const int* in_sizes, int n_in,
                              void* d_out, int out_size, void* d_ws, size_t ws_size,
                              hipStream_t stream) {
    const float* x   = (const float*)d_in[0];
    const void* edge = d_in[1];
    const void* batch= d_in[2];
    const float* W1l = (const float*)d_in[3];
    const float* W1r = (const float*)d_in[4];
    const float* b1  = (const float*)d_in[5];
    const float* W2l = (const float*)d_in[6];
    const float* W2r = (const float*)d_in[7];
    const float* b2  = (const float*)d_in[8];
    const float* Wh  = (const float*)d_in[9];
    const float* bh  = (const float*)d_in[10];
    float* out = (float*)d_out;

    char* p = (char*)d_ws;
    unsigned short* xb   = (unsigned short*)p; p += (size_t)NN * CIN * 2;   // 12.8 MB
    unsigned short* h1b  = (unsigned short*)p; p += (size_t)NN * CH * 2;    // 25.6 MB
    unsigned short* h2b  = (unsigned short*)p; p += (size_t)NN * CH * 2;    // 25.6 MB
    unsigned short* msgb = (unsigned short*)p; p += (size_t)NN * CH * 2;    // 25.6 MB
    unsigned short* W1lf = (unsigned short*)p; p += (size_t)CIN * CH * 2;
    unsigned short* W1rf = (unsigned short*)p; p += (size_t)CIN * CH * 2;
    unsigned short* W2lf = (unsigned short*)p; p += (size_t)CH * CH * 2;
    unsigned short* W2rf = (unsigned short*)p; p += (size_t)CH * CH * 2;
    int* bati  = (int*)p;       p += (size_t)NN * sizeof(int);
    int* deg   = (int*)p;       p += (size_t)NN * sizeof(int);
    int* rowstart = (int*)p;    p += (size_t)(NN + 1) * sizeof(int);
    int* cursor   = (int*)p;    p += (size_t)(NN + 1) * sizeof(int) + 4;   // keep 8B align
    int* eidx  = (int*)p;       p += (size_t)NE * sizeof(int);             // 6.4 MB
    int* flag  = (int*)p;       p += 256;

    k_detect<<<1, 128, 0, stream>>>(edge, flag);
    k_cvtbatch<<<(NN + 255) / 256, 256, 0, stream>>>(batch, flag, bati);

    hipMemsetAsync(deg, 0, NN * sizeof(int), stream);
    k_deg<<<1024, 256, 0, stream>>>(edge, flag, deg);
    k_scan<<<1, 1024, 0, stream>>>(deg, rowstart);
    hipMemcpyAsync(cursor, rowstart, NN * sizeof(int), hipMemcpyDeviceToDevice, stream);
    k_fill<<<4096, 256, 0, stream>>>(edge, flag, cursor, eidx);

    // conversions (independent of CSR build)
    k_cvtx<<<(NN * CIN / 8 + 255) / 256, 256, 0, stream>>>(x, xb, NN * CIN / 8);
    k_cvtW<<<4, 256, 0, stream>>>(W1l, CIN, CH, W1lf);
    k_cvtW<<<4, 256, 0, stream>>>(W1r, CIN, CH, W1rf);
    k_cvtW<<<8, 256, 0, stream>>>(W2l, CH, CH, W2lf);
    k_cvtW<<<8, 256, 0, stream>>>(W2r, CH, CH, W2rf);

    // layer 1
    k_gatherb<CIN><<<(NN + 3) / 4, 256, 0, stream>>>(xb, eidx, rowstart, msgb);
    k_sage_mfma<CIN><<<(NN + 63) / 64, 256, 0, stream>>>(msgb, xb, W1lf, W1rf, b1, h1b);

    // layer 2
    k_gatherb<CH><<<(NN + 3) / 4, 256, 0, stream>>>(h1b, eidx, rowstart, msgb);
    k_sage_mfma<CH><<<(NN + 63) / 64, 256, 0, stream>>>(msgb, h1b, W2lf, W2rf, b2, h2b);

    k_poolb<<<NG, 128, 0, stream>>>(h2b, bati, Wh, bh, out);
}

// Round 4
// 601.542 us; speedup vs baseline: 8.1191x; 1.2790x over previous
//
#include <hip/hip_runtime.h>

#define NN 100000
#define NE 1600000
#define CIN 64
#define CH 128
#define NCLS 8
#define NG 1000

#define SCAN_B 1024
#define NBLK ((NN + SCAN_B - 1) / SCAN_B)   // 98

typedef __attribute__((ext_vector_type(8))) short bf16x8;
typedef __attribute__((ext_vector_type(8))) unsigned short ushort8;
typedef __attribute__((ext_vector_type(4))) float f32x4;

__device__ __forceinline__ float bf2f(unsigned short u) {
    union { unsigned int i; float f; } c; c.i = ((unsigned int)u) << 16; return c.f;
}
__device__ __forceinline__ unsigned short f2bf(float f) {
    union { float f; unsigned int i; } c; c.f = f;
    unsigned int r = c.i + 0x7FFFu + ((c.i >> 16) & 1u);
    return (unsigned short)(r >> 16);
}

// ---------------- index width detection ----------------
__global__ void k_detect(const void* __restrict__ edge, int* __restrict__ flag) {
    const int* e32 = (const int*)edge;
    int t = threadIdx.x;              // 128 threads
    int v = e32[2 * t + 1];
    unsigned long long any = __ballot(v != 0);
    if (t == 0) flag[0] = (any == 0ull) ? 1 : 0;
}

__global__ void k_cvtbatch(const void* __restrict__ batch, const int* __restrict__ flag,
                           int* __restrict__ bati) {
    int i = blockIdx.x * blockDim.x + threadIdx.x;
    if (i >= NN) return;
    bati[i] = flag[0] ? (int)((const long long*)batch)[i] : ((const int*)batch)[i];
}

// ---------------- degree ----------------
__global__ __launch_bounds__(256) void k_deg(const void* __restrict__ edge, const int* __restrict__ flag,
                                             int* __restrict__ deg) {
    const bool w64 = flag[0] != 0;
    const int idx0 = blockIdx.x * blockDim.x + threadIdx.x;
    const int stride = gridDim.x * blockDim.x;
    if (w64) {
        const long long* d = (const long long*)edge + NE;
        for (int e = idx0; e < NE; e += stride) atomicAdd(&deg[(int)d[e]], 1);
    } else {
        const int* d = (const int*)edge + NE;
        for (int e = idx0; e < NE; e += stride) atomicAdd(&deg[d[e]], 1);
    }
}

// ---------------- hierarchical exclusive scan (3 phases) ----------------
__global__ __launch_bounds__(1024) void k_scan1(const int* __restrict__ deg, int* __restrict__ rowstart,
                                                int* __restrict__ blocksum) {
    __shared__ int buf[SCAN_B];
    const int i = blockIdx.x * SCAN_B + threadIdx.x;
    const int v = (i < NN) ? deg[i] : 0;
    buf[threadIdx.x] = v;
    __syncthreads();
    for (int off = 1; off < SCAN_B; off <<= 1) {
        int t = (threadIdx.x >= off) ? buf[threadIdx.x - off] : 0;
        __syncthreads();
        buf[threadIdx.x] += t;
        __syncthreads();
    }
    if (i < NN) rowstart[i] = buf[threadIdx.x] - v;   // exclusive within block
    if (threadIdx.x == SCAN_B - 1) blocksum[blockIdx.x] = buf[SCAN_B - 1];
}

__global__ __launch_bounds__(128) void k_scan2(const int* __restrict__ blocksum, int* __restrict__ blockoff,
                                               int* __restrict__ rowstart) {
    __shared__ int buf[128];
    const int v = (threadIdx.x < NBLK) ? blocksum[threadIdx.x] : 0;
    buf[threadIdx.x] = v;
    __syncthreads();
    for (int off = 1; off < 128; off <<= 1) {
        int t = (threadIdx.x >= off) ? buf[threadIdx.x - off] : 0;
        __syncthreads();
        buf[threadIdx.x] += t;
        __syncthreads();
    }
    if (threadIdx.x < NBLK) blockoff[threadIdx.x] = buf[threadIdx.x] - v;
    if (threadIdx.x == 127) rowstart[NN] = buf[127];   // == NE
}

__global__ __launch_bounds__(1024) void k_scan3(int* __restrict__ rowstart, const int* __restrict__ blockoff,
                                                int* __restrict__ cursor) {
    const int i = blockIdx.x * SCAN_B + threadIdx.x;
    if (i < NN) {
        int v = rowstart[i] + blockoff[blockIdx.x];
        rowstart[i] = v;
        cursor[i] = v;
    }
}

// ---------------- CSR fill ----------------
__global__ __launch_bounds__(256) void k_fill(const void* __restrict__ edge, const int* __restrict__ flag,
                                              int* __restrict__ cursor, int* __restrict__ eidx) {
    const bool w64 = flag[0] != 0;
    const int idx0 = blockIdx.x * blockDim.x + threadIdx.x;
    const int stride = gridDim.x * blockDim.x;
    if (w64) {
        const long long* e = (const long long*)edge;
        for (int i = idx0; i < NE; i += stride) {
            int s = (int)e[i];
            int d = (int)e[NE + i];
            int pos = atomicAdd(&cursor[d], 1);
            eidx[pos] = s;
        }
    } else {
        const int* e = (const int*)edge;
        for (int i = idx0; i < NE; i += stride) {
            int s = e[i];
            int d = e[NE + i];
            int pos = atomicAdd(&cursor[d], 1);
            eidx[pos] = s;
        }
    }
}

// ---------------- fp32 -> bf16 feature conversion ----------------
__global__ void k_cvtx(const float* __restrict__ x, unsigned short* __restrict__ xb, int total8) {
    int i = blockIdx.x * blockDim.x + threadIdx.x;
    if (i >= total8) return;
    float4 v0 = ((const float4*)x)[2 * i];
    float4 v1 = ((const float4*)x)[2 * i + 1];
    ushort8 o;
    o[0] = f2bf(v0.x); o[1] = f2bf(v0.y); o[2] = f2bf(v0.z); o[3] = f2bf(v0.w);
    o[4] = f2bf(v1.x); o[5] = f2bf(v1.y); o[6] = f2bf(v1.z); o[7] = f2bf(v1.w);
    ((ushort8*)xb)[i] = o;
}

// ---------------- weight -> fragment-ready bf16 layout ----------------
// W is [K][N] row-major fp32. Output: frag (nt, ks, lane) -> 8 bf16:
//   out[((nt*(K/32)+ks)*64+l)*8 + j] = bf16(W[ks*32 + (l>>4)*8 + j][nt*16 + (l&15)])
__global__ void k_cvtW(const float* __restrict__ W, int K, int N, unsigned short* __restrict__ out) {
    int idx = blockIdx.x * blockDim.x + threadIdx.x;
    int total = (N / 16) * (K / 32) * 64;
    if (idx >= total) return;
    int l = idx & 63;
    int ks = (idx >> 6) % (K / 32);
    int nt = (idx >> 6) / (K / 32);
    int krow = ks * 32 + (l >> 4) * 8;
    int col = nt * 16 + (l & 15);
    ushort8 o;
#pragma unroll
    for (int j = 0; j < 8; j++) o[j] = f2bf(W[(size_t)(krow + j) * N + col]);
    ((ushort8*)out)[idx] = o;
}

// ---------------- gather-mean over in-edges (bf16 features, fp32 accum) ----------------
template <int C>
__global__ __launch_bounds__(256) void k_gatherb(const unsigned short* __restrict__ feat,
                                                 const int* __restrict__ eidx,
                                                 const int* __restrict__ rowstart,
                                                 unsigned short* __restrict__ msg) {
    const int node = blockIdx.x * 4 + (threadIdx.x >> 6);
    if (node >= NN) return;
    const int lane = threadIdx.x & 63;
    const int lo = rowstart[node];
    const int hi = rowstart[node + 1];
    if (C == 64) {
        float acc = 0.f;
        for (int e = lo; e < hi; e++) {
            int s = eidx[e];
            acc += bf2f(feat[(size_t)s * 64 + lane]);
        }
        msg[(size_t)node * 64 + lane] = f2bf(acc / fmaxf((float)(hi - lo), 1.0f));
    } else {
        float a0 = 0.f, a1 = 0.f;
        for (int e = lo; e < hi; e++) {
            int s = eidx[e];
            ushort2 v = *(const ushort2*)&feat[(size_t)s * 128 + lane * 2];
            a0 += bf2f(v.x); a1 += bf2f(v.y);
        }
        float inv = 1.0f / fmaxf((float)(hi - lo), 1.0f);
        ushort2 o; o.x = f2bf(a0 * inv); o.y = f2bf(a1 * inv);
        *(ushort2*)&msg[(size_t)node * 128 + lane * 2] = o;
    }
}

// ---------------- fused SAGE layer via MFMA: out = relu(A1@B1 + A2@B2 + bias) ----------------
// A1,A2: [NN][K] bf16 row-major. B1,B2: fragment-ready (k_cvtW). out: [NN][128] bf16.
// Block = 256 thr (4 waves), each wave computes 16 rows x 128 cols.
template <int K>
__global__ __launch_bounds__(256) void k_sage_mfma(const unsigned short* __restrict__ A1,
                                                   const unsigned short* __restrict__ A2,
                                                   const unsigned short* __restrict__ B1,
                                                   const unsigned short* __restrict__ B2,
                                                   const float* __restrict__ bias,
                                                   unsigned short* __restrict__ out) {
    constexpr int KS = K / 32;
    const int wid = threadIdx.x >> 6;
    const int lane = threadIdx.x & 63;
    const int rowbase = blockIdx.x * 64 + wid * 16;
    const int arow = rowbase + (lane & 15);
    const int arowc = (arow < NN) ? arow : (NN - 1);
    const int kgrp = (lane >> 4) * 8;

    f32x4 acc[8];
#pragma unroll
    for (int nt = 0; nt < 8; nt++) {
        float bj = bias[nt * 16 + (lane & 15)];
        acc[nt][0] = bj; acc[nt][1] = bj; acc[nt][2] = bj; acc[nt][3] = bj;
    }

    const bf16x8* b1v = (const bf16x8*)B1;
    const bf16x8* b2v = (const bf16x8*)B2;
#pragma unroll
    for (int ks = 0; ks < KS; ks++) {
        bf16x8 a1 = *(const bf16x8*)&A1[(size_t)arowc * K + ks * 32 + kgrp];
        bf16x8 a2 = *(const bf16x8*)&A2[(size_t)arowc * K + ks * 32 + kgrp];
#pragma unroll
        for (int nt = 0; nt < 8; nt++) {
            acc[nt] = __builtin_amdgcn_mfma_f32_16x16x32_bf16(a1, b1v[(nt * KS + ks) * 64 + lane], acc[nt], 0, 0, 0);
            acc[nt] = __builtin_amdgcn_mfma_f32_16x16x32_bf16(a2, b2v[(nt * KS + ks) * 64 + lane], acc[nt], 0, 0, 0);
        }
    }

    const int colb = lane & 15;
    const int rhi = (lane >> 4) * 4;
#pragma unroll
    for (int nt = 0; nt < 8; nt++) {
#pragma unroll
        for (int r = 0; r < 4; r++) {
            int row = rowbase + rhi + r;
            if (row < NN)
                out[(size_t)row * 128 + nt * 16 + colb] = f2bf(fmaxf(acc[nt][r], 0.0f));
        }
    }
}

// ---------------- fused global-mean-pool + head (bf16 h, fp32 math) ----------------
__device__ __forceinline__ int lower_bound_dev(const int* __restrict__ a, int n, int key) {
    int lo = 0, hi = n;
    while (lo < hi) {
        int mid = (lo + hi) >> 1;
        if (a[mid] < key) lo = mid + 1; else hi = mid;
    }
    return lo;
}

__global__ __launch_bounds__(128) void k_poolb(const unsigned short* __restrict__ h,
                                               const int* __restrict__ batch,
                                               const float* __restrict__ Wh, const float* __restrict__ bh,
                                               float* __restrict__ out) {
    const int g = blockIdx.x;
    const int lo = lower_bound_dev(batch, NN, g);
    const int hi = lower_bound_dev(batch, NN, g + 1);
    const int j = threadIdx.x;
    float s = 0.f;
    for (int i = lo; i < hi; i++) s += bf2f(h[(size_t)i * CH + j]);
    __shared__ float pooled[CH];
    pooled[j] = s / fmaxf((float)(hi - lo), 1.0f);
    __syncthreads();
    if (j < NCLS) {
        float acc = bh[j];
#pragma unroll
        for (int k = 0; k < CH; k++) acc = fmaf(pooled[k], Wh[k * NCLS + j], acc);
        out[(size_t)g * NCLS + j] = acc;
    }
}

extern "C" void kernel_launch(void* const* d_in, const int* in_sizes, int n_in,
                              void* d_out, int out_size, void* d_ws, size_t ws_size,
                              hipStream_t stream) {
    const float* x   = (const float*)d_in[0];
    const void* edge = d_in[1];
    const void* batch= d_in[2];
    const float* W1l = (const float*)d_in[3];
    const float* W1r = (const float*)d_in[4];
    const float* b1  = (const float*)d_in[5];
    const float* W2l = (const float*)d_in[6];
    const float* W2r = (const float*)d_in[7];
    const float* b2  = (const float*)d_in[8];
    const float* Wh  = (const float*)d_in[9];
    const float* bh  = (const float*)d_in[10];
    float* out = (float*)d_out;

    char* p = (char*)d_ws;
    unsigned short* xb   = (unsigned short*)p; p += (size_t)NN * CIN * 2;   // 12.8 MB
    unsigned short* h1b  = (unsigned short*)p; p += (size_t)NN * CH * 2;    // 25.6 MB
    unsigned short* h2b  = (unsigned short*)p; p += (size_t)NN * CH * 2;    // 25.6 MB
    unsigned short* msgb = (unsigned short*)p; p += (size_t)NN * CH * 2;    // 25.6 MB
    unsigned short* W1lf = (unsigned short*)p; p += (size_t)CIN * CH * 2;
    unsigned short* W1rf = (unsigned short*)p; p += (size_t)CIN * CH * 2;
    unsigned short* W2lf = (unsigned short*)p; p += (size_t)CH * CH * 2;
    unsigned short* W2rf = (unsigned short*)p; p += (size_t)CH * CH * 2;
    int* bati  = (int*)p;       p += (size_t)NN * sizeof(int);
    int* deg   = (int*)p;       p += (size_t)NN * sizeof(int);
    int* rowstart = (int*)p;    p += (size_t)(NN + 1) * sizeof(int);
    int* cursor   = (int*)p;    p += (size_t)(NN + 1) * sizeof(int) + 4;   // keep 8B align
    int* eidx  = (int*)p;       p += (size_t)NE * sizeof(int);             // 6.4 MB
    int* blocksum = (int*)p;    p += (size_t)NBLK * sizeof(int);
    int* blockoff = (int*)p;    p += (size_t)NBLK * sizeof(int);
    int* flag  = (int*)p;       p += 256;

    k_detect<<<1, 128, 0, stream>>>(edge, flag);
    k_cvtbatch<<<(NN + 255) / 256, 256, 0, stream>>>(batch, flag, bati);

    hipMemsetAsync(deg, 0, NN * sizeof(int), stream);
    k_deg<<<1024, 256, 0, stream>>>(edge, flag, deg);
    k_scan1<<<NBLK, SCAN_B, 0, stream>>>(deg, rowstart, blocksum);
    k_scan2<<<1, 128, 0, stream>>>(blocksum, blockoff, rowstart);
    k_scan3<<<NBLK, SCAN_B, 0, stream>>>(rowstart, blockoff, cursor);
    k_fill<<<4096, 256, 0, stream>>>(edge, flag, cursor, eidx);

    // conversions (independent of CSR build)
    k_cvtx<<<(NN * CIN / 8 + 255) / 256, 256, 0, stream>>>(x, xb, NN * CIN / 8);
    k_cvtW<<<4, 256, 0, stream>>>(W1l, CIN, CH, W1lf);
    k_cvtW<<<4, 256, 0, stream>>>(W1r, CIN, CH, W1rf);
    k_cvtW<<<8, 256, 0, stream>>>(W2l, CH, CH, W2lf);
    k_cvtW<<<8, 256, 0, stream>>>(W2r, CH, CH, W2rf);

    // layer 1
    k_gatherb<CIN><<<(NN + 3) / 4, 256, 0, stream>>>(xb, eidx, rowstart, msgb);
    k_sage_mfma<CIN><<<(NN + 63) / 64, 256, 0, stream>>>(msgb, xb, W1lf, W1rf, b1, h1b);

    // layer 2
    k_gatherb<CH><<<(NN + 3) / 4, 256, 0, stream>>>(h1b, eidx, rowstart, msgb);
    k_sage_mfma<CH><<<(NN + 63) / 64, 256, 0, stream>>>(msgb, h1b, W2lf, W2rf, b2, h2b);

    k_poolb<<<NG, 128, 0, stream>>>(h2b, bati, Wh, bh, out);
}

// Round 5
// 413.490 us; speedup vs baseline: 11.8117x; 1.4548x over previous
//
#include <hip/hip_runtime.h>

#define NN 100000
#define NE 1600000
#define CIN 64
#define CH 128
#define NCLS 8
#define NG 1000

#define SCAN_B 1024
#define NBLK ((NN + SCAN_B - 1) / SCAN_B)   // 98

typedef __attribute__((ext_vector_type(8))) short bf16x8;
typedef __attribute__((ext_vector_type(8))) unsigned short ushort8;
typedef __attribute__((ext_vector_type(4))) float f32x4;

__device__ __forceinline__ float bf2f(unsigned short u) {
    union { unsigned int i; float f; } c; c.i = ((unsigned int)u) << 16; return c.f;
}
__device__ __forceinline__ unsigned short f2bf(float f) {
    union { float f; unsigned int i; } c; c.f = f;
    unsigned int r = c.i + 0x7FFFu + ((c.i >> 16) & 1u);
    return (unsigned short)(r >> 16);
}

// ---------------- index width detection ----------------
__global__ void k_detect(const void* __restrict__ edge, int* __restrict__ flag) {
    const int* e32 = (const int*)edge;
    int t = threadIdx.x;              // 128 threads
    int v = e32[2 * t + 1];
    unsigned long long any = __ballot(v != 0);
    if (t == 0) flag[0] = (any == 0ull) ? 1 : 0;
}

__global__ void k_cvtbatch(const void* __restrict__ batch, const int* __restrict__ flag,
                           int* __restrict__ bati) {
    int i = blockIdx.x * blockDim.x + threadIdx.x;
    if (i >= NN) return;
    bati[i] = flag[0] ? (int)((const long long*)batch)[i] : ((const int*)batch)[i];
}

// ---------------- degree ----------------
__global__ __launch_bounds__(256) void k_deg(const void* __restrict__ edge, const int* __restrict__ flag,
                                             int* __restrict__ deg) {
    const bool w64 = flag[0] != 0;
    const int idx0 = blockIdx.x * blockDim.x + threadIdx.x;
    const int stride = gridDim.x * blockDim.x;
    if (w64) {
        const long long* d = (const long long*)edge + NE;
        for (int e = idx0; e < NE; e += stride) atomicAdd(&deg[(int)d[e]], 1);
    } else {
        const int* d = (const int*)edge + NE;
        for (int e = idx0; e < NE; e += stride) atomicAdd(&deg[d[e]], 1);
    }
}

// ---------------- hierarchical exclusive scan (3 phases) ----------------
__global__ __launch_bounds__(1024) void k_scan1(const int* __restrict__ deg, int* __restrict__ rowstart,
                                                int* __restrict__ blocksum) {
    __shared__ int buf[SCAN_B];
    const int i = blockIdx.x * SCAN_B + threadIdx.x;
    const int v = (i < NN) ? deg[i] : 0;
    buf[threadIdx.x] = v;
    __syncthreads();
    for (int off = 1; off < SCAN_B; off <<= 1) {
        int t = (threadIdx.x >= off) ? buf[threadIdx.x - off] : 0;
        __syncthreads();
        buf[threadIdx.x] += t;
        __syncthreads();
    }
    if (i < NN) rowstart[i] = buf[threadIdx.x] - v;   // exclusive within block
    if (threadIdx.x == SCAN_B - 1) blocksum[blockIdx.x] = buf[SCAN_B - 1];
}

__global__ __launch_bounds__(128) void k_scan2(const int* __restrict__ blocksum, int* __restrict__ blockoff,
                                               int* __restrict__ rowstart) {
    __shared__ int buf[128];
    const int v = (threadIdx.x < NBLK) ? blocksum[threadIdx.x] : 0;
    buf[threadIdx.x] = v;
    __syncthreads();
    for (int off = 1; off < 128; off <<= 1) {
        int t = (threadIdx.x >= off) ? buf[threadIdx.x - off] : 0;
        __syncthreads();
        buf[threadIdx.x] += t;
        __syncthreads();
    }
    if (threadIdx.x < NBLK) blockoff[threadIdx.x] = buf[threadIdx.x] - v;
    if (threadIdx.x == 127) rowstart[NN] = buf[127];   // == NE
}

__global__ __launch_bounds__(1024) void k_scan3(int* __restrict__ rowstart, const int* __restrict__ blockoff,
                                                int* __restrict__ cursor) {
    const int i = blockIdx.x * SCAN_B + threadIdx.x;
    if (i < NN) {
        int v = rowstart[i] + blockoff[blockIdx.x];
        rowstart[i] = v;
        cursor[i] = v;
    }
}

// ---------------- CSR fill ----------------
__global__ __launch_bounds__(256) void k_fill(const void* __restrict__ edge, const int* __restrict__ flag,
                                              int* __restrict__ cursor, int* __restrict__ eidx) {
    const bool w64 = flag[0] != 0;
    const int idx0 = blockIdx.x * blockDim.x + threadIdx.x;
    const int stride = gridDim.x * blockDim.x;
    if (w64) {
        const long long* e = (const long long*)edge;
        for (int i = idx0; i < NE; i += stride) {
            int s = (int)e[i];
            int d = (int)e[NE + i];
            int pos = atomicAdd(&cursor[d], 1);
            eidx[pos] = s;
        }
    } else {
        const int* e = (const int*)edge;
        for (int i = idx0; i < NE; i += stride) {
            int s = e[i];
            int d = e[NE + i];
            int pos = atomicAdd(&cursor[d], 1);
            eidx[pos] = s;
        }
    }
}

// ---------------- fp32 -> bf16 feature conversion ----------------
__global__ void k_cvtx(const float* __restrict__ x, unsigned short* __restrict__ xb, int total8) {
    int i = blockIdx.x * blockDim.x + threadIdx.x;
    if (i >= total8) return;
    float4 v0 = ((const float4*)x)[2 * i];
    float4 v1 = ((const float4*)x)[2 * i + 1];
    ushort8 o;
    o[0] = f2bf(v0.x); o[1] = f2bf(v0.y); o[2] = f2bf(v0.z); o[3] = f2bf(v0.w);
    o[4] = f2bf(v1.x); o[5] = f2bf(v1.y); o[6] = f2bf(v1.z); o[7] = f2bf(v1.w);
    ((ushort8*)xb)[i] = o;
}

// ---------------- weight -> fragment-ready bf16 layout ----------------
// W is [K][N] row-major fp32. Output: frag (nt, ks, lane) -> 8 bf16:
//   out[((nt*(K/32)+ks)*64+l)*8 + j] = bf16(W[ks*32 + (l>>4)*8 + j][nt*16 + (l&15)])
__global__ void k_cvtW(const float* __restrict__ W, int K, int N, unsigned short* __restrict__ out) {
    int idx = blockIdx.x * blockDim.x + threadIdx.x;
    int total = (N / 16) * (K / 32) * 64;
    if (idx >= total) return;
    int l = idx & 63;
    int ks = (idx >> 6) % (K / 32);
    int nt = (idx >> 6) / (K / 32);
    int krow = ks * 32 + (l >> 4) * 8;
    int col = nt * 16 + (l & 15);
    ushort8 o;
#pragma unroll
    for (int j = 0; j < 8; j++) o[j] = f2bf(W[(size_t)(krow + j) * N + col]);
    ((ushort8*)out)[idx] = o;
}

// ---------------- gather-mean over in-edges, vectorized for MLP ----------------
// Wave = 64 lanes split into groups of G = C/8 lanes; each group owns one edge,
// each lane loads 16 B (8 bf16 channels). EPW = 64/G edges in flight per iter.
// Cross-group butterfly reduce at the end.
template <int C>
__global__ __launch_bounds__(256) void k_gatherv(const unsigned short* __restrict__ feat,
                                                 const int* __restrict__ eidx,
                                                 const int* __restrict__ rowstart,
                                                 unsigned short* __restrict__ msg) {
    constexpr int G = C / 8;          // lanes per row: 8 (C=64) or 16 (C=128)
    constexpr int EPW = 64 / G;       // edges in flight: 8 or 4
    const int node = blockIdx.x * 4 + (threadIdx.x >> 6);
    if (node >= NN) return;
    const int lane = threadIdx.x & 63;
    const int grp = lane / G;
    const int sub = lane % G;
    const int lo = rowstart[node];
    const int hi = rowstart[node + 1];

    float acc[8] = {0.f, 0.f, 0.f, 0.f, 0.f, 0.f, 0.f, 0.f};
    int e = lo + grp;
    // unrolled-by-2 main loop: two independent row loads in flight per group
    for (; e + EPW < hi; e += 2 * EPW) {
        int s0 = eidx[e];
        int s1 = eidx[e + EPW];
        ushort8 v0 = *(const ushort8*)&feat[(size_t)s0 * C + sub * 8];
        ushort8 v1 = *(const ushort8*)&feat[(size_t)s1 * C + sub * 8];
#pragma unroll
        for (int j = 0; j < 8; j++) acc[j] += bf2f(v0[j]) + bf2f(v1[j]);
    }
    if (e < hi) {
        int s0 = eidx[e];
        ushort8 v0 = *(const ushort8*)&feat[(size_t)s0 * C + sub * 8];
#pragma unroll
        for (int j = 0; j < 8; j++) acc[j] += bf2f(v0[j]);
    }

    // butterfly-sum across groups (lanes differing in bits >= log2(G))
#pragma unroll
    for (int off = G; off < 64; off <<= 1) {
#pragma unroll
        for (int j = 0; j < 8; j++) acc[j] += __shfl_xor(acc[j], off, 64);
    }

    if (grp == 0) {
        const float inv = 1.0f / fmaxf((float)(hi - lo), 1.0f);
        ushort8 o;
#pragma unroll
        for (int j = 0; j < 8; j++) o[j] = f2bf(acc[j] * inv);
        *(ushort8*)&msg[(size_t)node * C + sub * 8] = o;
    }
}

// ---------------- fused SAGE layer via MFMA: out = relu(A1@B1 + A2@B2 + bias) ----------------
// A1,A2: [NN][K] bf16 row-major. B1,B2: fragment-ready (k_cvtW). out: [NN][128] bf16.
// Block = 256 thr (4 waves), each wave computes 16 rows x 128 cols.
template <int K>
__global__ __launch_bounds__(256) void k_sage_mfma(const unsigned short* __restrict__ A1,
                                                   const unsigned short* __restrict__ A2,
                                                   const unsigned short* __restrict__ B1,
                                                   const unsigned short* __restrict__ B2,
                                                   const float* __restrict__ bias,
                                                   unsigned short* __restrict__ out) {
    constexpr int KS = K / 32;
    const int wid = threadIdx.x >> 6;
    const int lane = threadIdx.x & 63;
    const int rowbase = blockIdx.x * 64 + wid * 16;
    const int arow = rowbase + (lane & 15);
    const int arowc = (arow < NN) ? arow : (NN - 1);
    const int kgrp = (lane >> 4) * 8;

    f32x4 acc[8];
#pragma unroll
    for (int nt = 0; nt < 8; nt++) {
        float bj = bias[nt * 16 + (lane & 15)];
        acc[nt][0] = bj; acc[nt][1] = bj; acc[nt][2] = bj; acc[nt][3] = bj;
    }

    const bf16x8* b1v = (const bf16x8*)B1;
    const bf16x8* b2v = (const bf16x8*)B2;
#pragma unroll
    for (int ks = 0; ks < KS; ks++) {
        bf16x8 a1 = *(const bf16x8*)&A1[(size_t)arowc * K + ks * 32 + kgrp];
        bf16x8 a2 = *(const bf16x8*)&A2[(size_t)arowc * K + ks * 32 + kgrp];
#pragma unroll
        for (int nt = 0; nt < 8; nt++) {
            acc[nt] = __builtin_amdgcn_mfma_f32_16x16x32_bf16(a1, b1v[(nt * KS + ks) * 64 + lane], acc[nt], 0, 0, 0);
            acc[nt] = __builtin_amdgcn_mfma_f32_16x16x32_bf16(a2, b2v[(nt * KS + ks) * 64 + lane], acc[nt], 0, 0, 0);
        }
    }

    const int colb = lane & 15;
    const int rhi = (lane >> 4) * 4;
#pragma unroll
    for (int nt = 0; nt < 8; nt++) {
#pragma unroll
        for (int r = 0; r < 4; r++) {
            int row = rowbase + rhi + r;
            if (row < NN)
                out[(size_t)row * 128 + nt * 16 + colb] = f2bf(fmaxf(acc[nt][r], 0.0f));
        }
    }
}

// ---------------- fused global-mean-pool + head (bf16 h, fp32 math) ----------------
__device__ __forceinline__ int lower_bound_dev(const int* __restrict__ a, int n, int key) {
    int lo = 0, hi = n;
    while (lo < hi) {
        int mid = (lo + hi) >> 1;
        if (a[mid] < key) lo = mid + 1; else hi = mid;
    }
    return lo;
}

__global__ __launch_bounds__(128) void k_poolb(const unsigned short* __restrict__ h,
                                               const int* __restrict__ batch,
                                               const float* __restrict__ Wh, const float* __restrict__ bh,
                                               float* __restrict__ out) {
    const int g = blockIdx.x;
    const int lo = lower_bound_dev(batch, NN, g);
    const int hi = lower_bound_dev(batch, NN, g + 1);
    const int j = threadIdx.x;
    float s = 0.f;
    for (int i = lo; i < hi; i++) s += bf2f(h[(size_t)i * CH + j]);
    __shared__ float pooled[CH];
    pooled[j] = s / fmaxf((float)(hi - lo), 1.0f);
    __syncthreads();
    if (j < NCLS) {
        float acc = bh[j];
#pragma unroll
        for (int k = 0; k < CH; k++) acc = fmaf(pooled[k], Wh[k * NCLS + j], acc);
        out[(size_t)g * NCLS + j] = acc;
    }
}

extern "C" void kernel_launch(void* const* d_in, const int* in_sizes, int n_in,
                              void* d_out, int out_size, void* d_ws, size_t ws_size,
                              hipStream_t stream) {
    const float* x   = (const float*)d_in[0];
    const void* edge = d_in[1];
    const void* batch= d_in[2];
    const float* W1l = (const float*)d_in[3];
    const float* W1r = (const float*)d_in[4];
    const float* b1  = (const float*)d_in[5];
    const float* W2l = (const float*)d_in[6];
    const float* W2r = (const float*)d_in[7];
    const float* b2  = (const float*)d_in[8];
    const float* Wh  = (const float*)d_in[9];
    const float* bh  = (const float*)d_in[10];
    float* out = (float*)d_out;

    char* p = (char*)d_ws;
    unsigned short* xb   = (unsigned short*)p; p += (size_t)NN * CIN * 2;   // 12.8 MB
    unsigned short* h1b  = (unsigned short*)p; p += (size_t)NN * CH * 2;    // 25.6 MB
    unsigned short* h2b  = (unsigned short*)p; p += (size_t)NN * CH * 2;    // 25.6 MB
    unsigned short* msgb = (unsigned short*)p; p += (size_t)NN * CH * 2;    // 25.6 MB
    unsigned short* W1lf = (unsigned short*)p; p += (size_t)CIN * CH * 2;
    unsigned short* W1rf = (unsigned short*)p; p += (size_t)CIN * CH * 2;
    unsigned short* W2lf = (unsigned short*)p; p += (size_t)CH * CH * 2;
    unsigned short* W2rf = (unsigned short*)p; p += (size_t)CH * CH * 2;
    int* bati  = (int*)p;       p += (size_t)NN * sizeof(int);
    int* deg   = (int*)p;       p += (size_t)NN * sizeof(int);
    int* rowstart = (int*)p;    p += (size_t)(NN + 1) * sizeof(int);
    int* cursor   = (int*)p;    p += (size_t)(NN + 1) * sizeof(int) + 4;   // keep 8B align
    int* eidx  = (int*)p;       p += (size_t)NE * sizeof(int);             // 6.4 MB
    int* blocksum = (int*)p;    p += (size_t)NBLK * sizeof(int);
    int* blockoff = (int*)p;    p += (size_t)NBLK * sizeof(int);
    int* flag  = (int*)p;       p += 256;

    k_detect<<<1, 128, 0, stream>>>(edge, flag);
    k_cvtbatch<<<(NN + 255) / 256, 256, 0, stream>>>(batch, flag, bati);

    hipMemsetAsync(deg, 0, NN * sizeof(int), stream);
    k_deg<<<1024, 256, 0, stream>>>(edge, flag, deg);
    k_scan1<<<NBLK, SCAN_B, 0, stream>>>(deg, rowstart, blocksum);
    k_scan2<<<1, 128, 0, stream>>>(blocksum, blockoff, rowstart);
    k_scan3<<<NBLK, SCAN_B, 0, stream>>>(rowstart, blockoff, cursor);
    k_fill<<<4096, 256, 0, stream>>>(edge, flag, cursor, eidx);

    // conversions (independent of CSR build)
    k_cvtx<<<(NN * CIN / 8 + 255) / 256, 256, 0, stream>>>(x, xb, NN * CIN / 8);
    k_cvtW<<<4, 256, 0, stream>>>(W1l, CIN, CH, W1lf);
    k_cvtW<<<4, 256, 0, stream>>>(W1r, CIN, CH, W1rf);
    k_cvtW<<<8, 256, 0, stream>>>(W2l, CH, CH, W2lf);
    k_cvtW<<<8, 256, 0, stream>>>(W2r, CH, CH, W2rf);

    // layer 1
    k_gatherv<CIN><<<(NN + 3) / 4, 256, 0, stream>>>(xb, eidx, rowstart, msgb);
    k_sage_mfma<CIN><<<(NN + 63) / 64, 256, 0, stream>>>(msgb, xb, W1lf, W1rf, b1, h1b);

    // layer 2
    k_gatherv<CH><<<(NN + 3) / 4, 256, 0, stream>>>(h1b, eidx, rowstart, msgb);
    k_sage_mfma<CH><<<(NN + 63) / 64, 256, 0, stream>>>(msgb, h1b, W2lf, W2rf, b2, h2b);

    k_poolb<<<NG, 128, 0, stream>>>(h2b, bati, Wh, bh, out);
}

// Round 6
// 353.172 us; speedup vs baseline: 13.8290x; 1.1708x over previous
//
#include <hip/hip_runtime.h>

#define NN 100000
#define NE 1600000
#define CIN 64
#define CH 128
#define NCLS 8
#define NG 1000

#define SCAN_B 1024
#define NBLK ((NN + SCAN_B - 1) / SCAN_B)   // 98

#define NPART 8
#define PART_NODES ((NN + NPART - 1) / NPART)   // 12500
#define FILL_BPP 256                             // blocks per partition cohort

typedef __attribute__((ext_vector_type(8))) short bf16x8;
typedef __attribute__((ext_vector_type(8))) unsigned short ushort8;
typedef __attribute__((ext_vector_type(4))) float f32x4;

__device__ __forceinline__ float bf2f(unsigned short u) {
    union { unsigned int i; float f; } c; c.i = ((unsigned int)u) << 16; return c.f;
}
__device__ __forceinline__ unsigned short f2bf(float f) {
    union { float f; unsigned int i; } c; c.f = f;
    unsigned int r = c.i + 0x7FFFu + ((c.i >> 16) & 1u);
    return (unsigned short)(r >> 16);
}

// ---------------- index width detection ----------------
__global__ void k_detect(const void* __restrict__ edge, int* __restrict__ flag) {
    const int* e32 = (const int*)edge;
    int t = threadIdx.x;              // 128 threads
    int v = e32[2 * t + 1];
    unsigned long long any = __ballot(v != 0);
    if (t == 0) flag[0] = (any == 0ull) ? 1 : 0;
}

__global__ void k_cvtbatch(const void* __restrict__ batch, const int* __restrict__ flag,
                           int* __restrict__ bati) {
    int i = blockIdx.x * blockDim.x + threadIdx.x;
    if (i >= NN) return;
    bati[i] = flag[0] ? (int)((const long long*)batch)[i] : ((const int*)batch)[i];
}

// ---------------- edge convert to int32 + degree accumulate ----------------
__global__ __launch_bounds__(256) void k_cvt_edge(const void* __restrict__ edge, const int* __restrict__ flag,
                                                  int* __restrict__ srci, int* __restrict__ dsti,
                                                  int* __restrict__ deg) {
    const bool w64 = flag[0] != 0;
    const int idx0 = blockIdx.x * blockDim.x + threadIdx.x;
    const int stride = gridDim.x * blockDim.x;
    if (w64) {
        const long long* e = (const long long*)edge;
        for (int i = idx0; i < NE; i += stride) {
            int s = (int)e[i];
            int d = (int)e[NE + i];
            srci[i] = s;
            dsti[i] = d;
            atomicAdd(&deg[d], 1);
        }
    } else {
        const int* e = (const int*)edge;
        for (int i = idx0; i < NE; i += stride) {
            int s = e[i];
            int d = e[NE + i];
            srci[i] = s;
            dsti[i] = d;
            atomicAdd(&deg[d], 1);
        }
    }
}

// ---------------- hierarchical exclusive scan (3 phases) ----------------
__global__ __launch_bounds__(1024) void k_scan1(const int* __restrict__ deg, int* __restrict__ rowstart,
                                                int* __restrict__ blocksum) {
    __shared__ int buf[SCAN_B];
    const int i = blockIdx.x * SCAN_B + threadIdx.x;
    const int v = (i < NN) ? deg[i] : 0;
    buf[threadIdx.x] = v;
    __syncthreads();
    for (int off = 1; off < SCAN_B; off <<= 1) {
        int t = (threadIdx.x >= off) ? buf[threadIdx.x - off] : 0;
        __syncthreads();
        buf[threadIdx.x] += t;
        __syncthreads();
    }
    if (i < NN) rowstart[i] = buf[threadIdx.x] - v;   // exclusive within block
    if (threadIdx.x == SCAN_B - 1) blocksum[blockIdx.x] = buf[SCAN_B - 1];
}

__global__ __launch_bounds__(128) void k_scan2(const int* __restrict__ blocksum, int* __restrict__ blockoff,
                                               int* __restrict__ rowstart) {
    __shared__ int buf[128];
    const int v = (threadIdx.x < NBLK) ? blocksum[threadIdx.x] : 0;
    buf[threadIdx.x] = v;
    __syncthreads();
    for (int off = 1; off < 128; off <<= 1) {
        int t = (threadIdx.x >= off) ? buf[threadIdx.x - off] : 0;
        __syncthreads();
        buf[threadIdx.x] += t;
        __syncthreads();
    }
    if (threadIdx.x < NBLK) blockoff[threadIdx.x] = buf[threadIdx.x] - v;
    if (threadIdx.x == 127) rowstart[NN] = buf[127];   // == NE
}

__global__ __launch_bounds__(1024) void k_scan3(int* __restrict__ rowstart, const int* __restrict__ blockoff,
                                                int* __restrict__ cursor) {
    const int i = blockIdx.x * SCAN_B + threadIdx.x;
    if (i < NN) {
        int v = rowstart[i] + blockoff[blockIdx.x];
        rowstart[i] = v;
        cursor[i] = v;
    }
}

// ---------------- CSR fill, XCD-partitioned ----------------
// Cohort p = blocks with blockIdx%8==p (round-robin XCD dispatch => cohort on one
// XCD). Cohort p keeps only edges with dst in [p*PART_NODES,(p+1)*PART_NODES):
// its eidx window is contiguous (~800 KB) and written by one XCD's L2 only ->
// full-line evictions, no cross-XCD partial-line write amplification.
__global__ __launch_bounds__(256) void k_fillx(const int* __restrict__ srci, const int* __restrict__ dsti,
                                               int* __restrict__ cursor, int* __restrict__ eidx) {
    const int part = blockIdx.x & (NPART - 1);
    const int b    = blockIdx.x / NPART;
    const int lo_node = part * PART_NODES;
    const int hi_node = lo_node + PART_NODES;   // NN not multiple-critical: dst < NN < 8*12500
    const int stride = FILL_BPP * 256;
    for (int i = b * 256 + threadIdx.x; i < NE; i += stride) {
        int d = dsti[i];
        if (d >= lo_node && d < hi_node) {
            int pos = atomicAdd(&cursor[d], 1);
            eidx[pos] = srci[i];
        }
    }
}

// ---------------- fp32 -> bf16 feature conversion ----------------
__global__ void k_cvtx(const float* __restrict__ x, unsigned short* __restrict__ xb, int total8) {
    int i = blockIdx.x * blockDim.x + threadIdx.x;
    if (i >= total8) return;
    float4 v0 = ((const float4*)x)[2 * i];
    float4 v1 = ((const float4*)x)[2 * i + 1];
    ushort8 o;
    o[0] = f2bf(v0.x); o[1] = f2bf(v0.y); o[2] = f2bf(v0.z); o[3] = f2bf(v0.w);
    o[4] = f2bf(v1.x); o[5] = f2bf(v1.y); o[6] = f2bf(v1.z); o[7] = f2bf(v1.w);
    ((ushort8*)xb)[i] = o;
}

// ---------------- weight -> fragment-ready bf16 layout ----------------
// W is [K][N] row-major fp32. Output: frag (nt, ks, lane) -> 8 bf16:
//   out[((nt*(K/32)+ks)*64+l)*8 + j] = bf16(W[ks*32 + (l>>4)*8 + j][nt*16 + (l&15)])
__global__ void k_cvtW(const float* __restrict__ W, int K, int N, unsigned short* __restrict__ out) {
    int idx = blockIdx.x * blockDim.x + threadIdx.x;
    int total = (N / 16) * (K / 32) * 64;
    if (idx >= total) return;
    int l = idx & 63;
    int ks = (idx >> 6) % (K / 32);
    int nt = (idx >> 6) / (K / 32);
    int krow = ks * 32 + (l >> 4) * 8;
    int col = nt * 16 + (l & 15);
    ushort8 o;
#pragma unroll
    for (int j = 0; j < 8; j++) o[j] = f2bf(W[(size_t)(krow + j) * N + col]);
    ((ushort8*)out)[idx] = o;
}

// ---------------- gather-mean over in-edges, vectorized for MLP ----------------
// Wave = 64 lanes split into groups of G = C/8 lanes; each group owns one edge,
// each lane loads 16 B (8 bf16 channels). EPW = 64/G edges in flight per iter.
template <int C>
__global__ __launch_bounds__(256) void k_gatherv(const unsigned short* __restrict__ feat,
                                                 const int* __restrict__ eidx,
                                                 const int* __restrict__ rowstart,
                                                 unsigned short* __restrict__ msg) {
    constexpr int G = C / 8;          // lanes per row: 8 (C=64) or 16 (C=128)
    constexpr int EPW = 64 / G;       // edges in flight: 8 or 4
    const int node = blockIdx.x * 4 + (threadIdx.x >> 6);
    if (node >= NN) return;
    const int lane = threadIdx.x & 63;
    const int grp = lane / G;
    const int sub = lane % G;
    const int lo = rowstart[node];
    const int hi = rowstart[node + 1];

    float acc[8] = {0.f, 0.f, 0.f, 0.f, 0.f, 0.f, 0.f, 0.f};
    int e = lo + grp;
    for (; e + EPW < hi; e += 2 * EPW) {
        int s0 = eidx[e];
        int s1 = eidx[e + EPW];
        ushort8 v0 = *(const ushort8*)&feat[(size_t)s0 * C + sub * 8];
        ushort8 v1 = *(const ushort8*)&feat[(size_t)s1 * C + sub * 8];
#pragma unroll
        for (int j = 0; j < 8; j++) acc[j] += bf2f(v0[j]) + bf2f(v1[j]);
    }
    if (e < hi) {
        int s0 = eidx[e];
        ushort8 v0 = *(const ushort8*)&feat[(size_t)s0 * C + sub * 8];
#pragma unroll
        for (int j = 0; j < 8; j++) acc[j] += bf2f(v0[j]);
    }

#pragma unroll
    for (int off = G; off < 64; off <<= 1) {
#pragma unroll
        for (int j = 0; j < 8; j++) acc[j] += __shfl_xor(acc[j], off, 64);
    }

    if (grp == 0) {
        const float inv = 1.0f / fmaxf((float)(hi - lo), 1.0f);
        ushort8 o;
#pragma unroll
        for (int j = 0; j < 8; j++) o[j] = f2bf(acc[j] * inv);
        *(ushort8*)&msg[(size_t)node * C + sub * 8] = o;
    }
}

// ---------------- fused SAGE layer via MFMA: out = relu(A1@B1 + A2@B2 + bias) ----------------
// A1,A2: [NN][K] bf16 row-major. B1,B2: fragment-ready (k_cvtW). out: [NN][128] bf16.
template <int K>
__global__ __launch_bounds__(256) void k_sage_mfma(const unsigned short* __restrict__ A1,
                                                   const unsigned short* __restrict__ A2,
                                                   const unsigned short* __restrict__ B1,
                                                   const unsigned short* __restrict__ B2,
                                                   const float* __restrict__ bias,
                                                   unsigned short* __restrict__ out) {
    constexpr int KS = K / 32;
    const int wid = threadIdx.x >> 6;
    const int lane = threadIdx.x & 63;
    const int rowbase = blockIdx.x * 64 + wid * 16;
    const int arow = rowbase + (lane & 15);
    const int arowc = (arow < NN) ? arow : (NN - 1);
    const int kgrp = (lane >> 4) * 8;

    f32x4 acc[8];
#pragma unroll
    for (int nt = 0; nt < 8; nt++) {
        float bj = bias[nt * 16 + (lane & 15)];
        acc[nt][0] = bj; acc[nt][1] = bj; acc[nt][2] = bj; acc[nt][3] = bj;
    }

    const bf16x8* b1v = (const bf16x8*)B1;
    const bf16x8* b2v = (const bf16x8*)B2;
#pragma unroll
    for (int ks = 0; ks < KS; ks++) {
        bf16x8 a1 = *(const bf16x8*)&A1[(size_t)arowc * K + ks * 32 + kgrp];
        bf16x8 a2 = *(const bf16x8*)&A2[(size_t)arowc * K + ks * 32 + kgrp];
#pragma unroll
        for (int nt = 0; nt < 8; nt++) {
            acc[nt] = __builtin_amdgcn_mfma_f32_16x16x32_bf16(a1, b1v[(nt * KS + ks) * 64 + lane], acc[nt], 0, 0, 0);
            acc[nt] = __builtin_amdgcn_mfma_f32_16x16x32_bf16(a2, b2v[(nt * KS + ks) * 64 + lane], acc[nt], 0, 0, 0);
        }
    }

    const int colb = lane & 15;
    const int rhi = (lane >> 4) * 4;
#pragma unroll
    for (int nt = 0; nt < 8; nt++) {
#pragma unroll
        for (int r = 0; r < 4; r++) {
            int row = rowbase + rhi + r;
            if (row < NN)
                out[(size_t)row * 128 + nt * 16 + colb] = f2bf(fmaxf(acc[nt][r], 0.0f));
        }
    }
}

// ---------------- fused global-mean-pool + head (bf16 h, fp32 math) ----------------
__device__ __forceinline__ int lower_bound_dev(const int* __restrict__ a, int n, int key) {
    int lo = 0, hi = n;
    while (lo < hi) {
        int mid = (lo + hi) >> 1;
        if (a[mid] < key) lo = mid + 1; else hi = mid;
    }
    return lo;
}

__global__ __launch_bounds__(128) void k_poolb(const unsigned short* __restrict__ h,
                                               const int* __restrict__ batch,
                                               const float* __restrict__ Wh, const float* __restrict__ bh,
                                               float* __restrict__ out) {
    const int g = blockIdx.x;
    const int lo = lower_bound_dev(batch, NN, g);
    const int hi = lower_bound_dev(batch, NN, g + 1);
    const int j = threadIdx.x;
    float s = 0.f;
    for (int i = lo; i < hi; i++) s += bf2f(h[(size_t)i * CH + j]);
    __shared__ float pooled[CH];
    pooled[j] = s / fmaxf((float)(hi - lo), 1.0f);
    __syncthreads();
    if (j < NCLS) {
        float acc = bh[j];
#pragma unroll
        for (int k = 0; k < CH; k++) acc = fmaf(pooled[k], Wh[k * NCLS + j], acc);
        out[(size_t)g * NCLS + j] = acc;
    }
}

extern "C" void kernel_launch(void* const* d_in, const int* in_sizes, int n_in,
                              void* d_out, int out_size, void* d_ws, size_t ws_size,
                              hipStream_t stream) {
    const float* x   = (const float*)d_in[0];
    const void* edge = d_in[1];
    const void* batch= d_in[2];
    const float* W1l = (const float*)d_in[3];
    const float* W1r = (const float*)d_in[4];
    const float* b1  = (const float*)d_in[5];
    const float* W2l = (const float*)d_in[6];
    const float* W2r = (const float*)d_in[7];
    const float* b2  = (const float*)d_in[8];
    const float* Wh  = (const float*)d_in[9];
    const float* bh  = (const float*)d_in[10];
    float* out = (float*)d_out;

    char* p = (char*)d_ws;
    unsigned short* xb   = (unsigned short*)p; p += (size_t)NN * CIN * 2;   // 12.8 MB
    unsigned short* h1b  = (unsigned short*)p; p += (size_t)NN * CH * 2;    // 25.6 MB
    unsigned short* h2b  = (unsigned short*)p; p += (size_t)NN * CH * 2;    // 25.6 MB
    unsigned short* msgb = (unsigned short*)p; p += (size_t)NN * CH * 2;    // 25.6 MB
    unsigned short* W1lf = (unsigned short*)p; p += (size_t)CIN * CH * 2;
    unsigned short* W1rf = (unsigned short*)p; p += (size_t)CIN * CH * 2;
    unsigned short* W2lf = (unsigned short*)p; p += (size_t)CH * CH * 2;
    unsigned short* W2rf = (unsigned short*)p; p += (size_t)CH * CH * 2;
    int* bati  = (int*)p;       p += (size_t)NN * sizeof(int);
    int* deg   = (int*)p;       p += (size_t)NN * sizeof(int);
    int* rowstart = (int*)p;    p += (size_t)(NN + 1) * sizeof(int);
    int* cursor   = (int*)p;    p += (size_t)(NN + 1) * sizeof(int) + 4;   // keep 8B align
    int* srci  = (int*)p;       p += (size_t)NE * sizeof(int);             // 6.4 MB
    int* dsti  = (int*)p;       p += (size_t)NE * sizeof(int);             // 6.4 MB
    int* eidx  = (int*)p;       p += (size_t)NE * sizeof(int);             // 6.4 MB
    int* blocksum = (int*)p;    p += (size_t)NBLK * sizeof(int);
    int* blockoff = (int*)p;    p += (size_t)NBLK * sizeof(int);
    int* flag  = (int*)p;       p += 256;

    k_detect<<<1, 128, 0, stream>>>(edge, flag);
    k_cvtbatch<<<(NN + 255) / 256, 256, 0, stream>>>(batch, flag, bati);

    hipMemsetAsync(deg, 0, NN * sizeof(int), stream);
    k_cvt_edge<<<2048, 256, 0, stream>>>(edge, flag, srci, dsti, deg);
    k_scan1<<<NBLK, SCAN_B, 0, stream>>>(deg, rowstart, blocksum);
    k_scan2<<<1, 128, 0, stream>>>(blocksum, blockoff, rowstart);
    k_scan3<<<NBLK, SCAN_B, 0, stream>>>(rowstart, blockoff, cursor);
    k_fillx<<<NPART * FILL_BPP, 256, 0, stream>>>(srci, dsti, cursor, eidx);

    // conversions (independent of CSR build)
    k_cvtx<<<(NN * CIN / 8 + 255) / 256, 256, 0, stream>>>(x, xb, NN * CIN / 8);
    k_cvtW<<<4, 256, 0, stream>>>(W1l, CIN, CH, W1lf);
    k_cvtW<<<4, 256, 0, stream>>>(W1r, CIN, CH, W1rf);
    k_cvtW<<<8, 256, 0, stream>>>(W2l, CH, CH, W2lf);
    k_cvtW<<<8, 256, 0, stream>>>(W2r, CH, CH, W2rf);

    // layer 1
    k_gatherv<CIN><<<(NN + 3) / 4, 256, 0, stream>>>(xb, eidx, rowstart, msgb);
    k_sage_mfma<CIN><<<(NN + 63) / 64, 256, 0, stream>>>(msgb, xb, W1lf, W1rf, b1, h1b);

    // layer 2
    k_gatherv<CH><<<(NN + 3) / 4, 256, 0, stream>>>(h1b, eidx, rowstart, msgb);
    k_sage_mfma<CH><<<(NN + 63) / 64, 256, 0, stream>>>(msgb, h1b, W2lf, W2rf, b2, h2b);

    k_poolb<<<NG, 128, 0, stream>>>(h2b, bati, Wh, bh, out);
}

// Round 7
// 348.891 us; speedup vs baseline: 13.9987x; 1.0123x over previous
//
#include <hip/hip_runtime.h>

#define NN 100000
#define NE 1600000
#define CIN 64
#define CH 128
#define NCLS 8
#define NG 1000

#define SCAN_B 1024
#define NBLK ((NN + SCAN_B - 1) / SCAN_B)   // 98

#define NPART 8
#define PART_NODES ((NN + NPART - 1) / NPART)   // 12500
#define FILL_BPP 256                             // blocks per partition cohort

typedef __attribute__((ext_vector_type(8))) short bf16x8;
typedef __attribute__((ext_vector_type(8))) unsigned short ushort8;
typedef __attribute__((ext_vector_type(4))) float f32x4;

__device__ __forceinline__ float bf2f(unsigned short u) {
    union { unsigned int i; float f; } c; c.i = ((unsigned int)u) << 16; return c.f;
}
__device__ __forceinline__ unsigned short f2bf(float f) {
    union { float f; unsigned int i; } c; c.f = f;
    unsigned int r = c.i + 0x7FFFu + ((c.i >> 16) & 1u);
    return (unsigned short)(r >> 16);
}

// Per-wave int64-vs-int32 detection: odd int32 slots are all zero iff int64.
// Random src values in [0,100000) make a false positive impossible.
__device__ __forceinline__ bool is_w64(const void* __restrict__ edge) {
    const int* e32 = (const int*)edge;
    int v = e32[2 * (threadIdx.x & 63) + 1];
    return __ballot(v != 0) == 0ull;
}

// ---------------- edge+batch convert (int32 packed) + degree ----------------
__global__ __launch_bounds__(256) void k_cvt(const void* __restrict__ edge, const void* __restrict__ batch,
                                             int2* __restrict__ ed, int* __restrict__ deg,
                                             int* __restrict__ bati) {
    const bool w64 = is_w64(edge);
    const int idx0 = blockIdx.x * blockDim.x + threadIdx.x;
    const int stride = gridDim.x * blockDim.x;
    if (w64) {
        const long long* e = (const long long*)edge;
        for (int i = idx0; i < NE; i += stride) {
            int s = (int)e[i];
            int d = (int)e[NE + i];
            ed[i] = make_int2(s, d);
            atomicAdd(&deg[d], 1);
        }
        const long long* b = (const long long*)batch;
        for (int i = idx0; i < NN; i += stride) bati[i] = (int)b[i];
    } else {
        const int* e = (const int*)edge;
        for (int i = idx0; i < NE; i += stride) {
            int s = e[i];
            int d = e[NE + i];
            ed[i] = make_int2(s, d);
            atomicAdd(&deg[d], 1);
        }
        const int* b = (const int*)batch;
        for (int i = idx0; i < NN; i += stride) bati[i] = b[i];
    }
}

// ---------------- single-kernel exclusive scan (decoupled lookback) ----------------
// 98 blocks x 1024 thr = 16 waves/block -> 2 blocks/CU -> all 98 co-resident on
// 49 of 256 CUs, so spinning on predecessors cannot deadlock.
__global__ __launch_bounds__(1024) void k_scan_all(const int* __restrict__ deg,
                                                   unsigned long long* __restrict__ pv,
                                                   int* __restrict__ rowstart, int* __restrict__ cursor) {
    __shared__ int buf[SCAN_B];
    __shared__ int s_off;
    const int bid = blockIdx.x;
    const int i = bid * SCAN_B + threadIdx.x;
    const int v = (i < NN) ? deg[i] : 0;
    buf[threadIdx.x] = v;
    __syncthreads();
    for (int off = 1; off < SCAN_B; off <<= 1) {
        int t = (threadIdx.x >= off) ? buf[threadIdx.x - off] : 0;
        __syncthreads();
        buf[threadIdx.x] += t;
        __syncthreads();
    }
    if (threadIdx.x == SCAN_B - 1)
        __hip_atomic_store(&pv[bid], (1ull << 32) | (unsigned long long)(unsigned)buf[SCAN_B - 1],
                           __ATOMIC_RELEASE, __HIP_MEMORY_SCOPE_AGENT);
    if (threadIdx.x < 64) {
        int off = 0;
        for (int j = (int)threadIdx.x; j < bid; j += 64) {
            unsigned long long p;
            do {
                p = __hip_atomic_load(&pv[j], __ATOMIC_ACQUIRE, __HIP_MEMORY_SCOPE_AGENT);
            } while (!(p >> 32));
            off += (int)(unsigned)p;
        }
#pragma unroll
        for (int s = 1; s < 64; s <<= 1) off += __shfl_xor(off, s, 64);
        if (threadIdx.x == 0) s_off = off;
    }
    __syncthreads();
    if (i < NN) {
        int r = s_off + buf[threadIdx.x] - v;
        rowstart[i] = r;
        cursor[i] = r;
    }
    if (i == 0) rowstart[NN] = NE;   // degrees sum to NE by construction
}

// ---------------- CSR fill, XCD-partitioned, sequential int4 edge stream ----------------
__global__ __launch_bounds__(256) void k_fillx(const int2* __restrict__ ed,
                                               int* __restrict__ cursor, int* __restrict__ eidx) {
    const int part = blockIdx.x & (NPART - 1);
    const int b    = blockIdx.x >> 3;
    const int lo_node = part * PART_NODES;
    const int hi_node = lo_node + PART_NODES;
    const int stride = FILL_BPP * 256 * 2;
    for (int i = (b * 256 + threadIdx.x) * 2; i < NE; i += stride) {
        int4 two = *(const int4*)&ed[i];
        if (two.y >= lo_node && two.y < hi_node) {
            int pos = atomicAdd(&cursor[two.y], 1);
            eidx[pos] = two.x;
        }
        if (two.w >= lo_node && two.w < hi_node) {
            int pos = atomicAdd(&cursor[two.w], 1);
            eidx[pos] = two.z;
        }
    }
}

// ---------------- fp32 -> bf16 feature conversion ----------------
__global__ void k_cvtx(const float* __restrict__ x, unsigned short* __restrict__ xb, int total8) {
    int i = blockIdx.x * blockDim.x + threadIdx.x;
    if (i >= total8) return;
    float4 v0 = ((const float4*)x)[2 * i];
    float4 v1 = ((const float4*)x)[2 * i + 1];
    ushort8 o;
    o[0] = f2bf(v0.x); o[1] = f2bf(v0.y); o[2] = f2bf(v0.z); o[3] = f2bf(v0.w);
    o[4] = f2bf(v1.x); o[5] = f2bf(v1.y); o[6] = f2bf(v1.z); o[7] = f2bf(v1.w);
    ((ushort8*)xb)[i] = o;
}

// ---------------- all four weights -> fragment-ready bf16, one kernel ----------------
// frag (nt, ks, lane) -> 8 bf16: out[((nt*(K/32)+ks)*64+l)*8+j] =
//   bf16(W[ks*32+(l>>4)*8+j][nt*16+(l&15)]), W row-major [K][128].
__global__ void k_cvtWall(const float* __restrict__ W1l, const float* __restrict__ W1r,
                          const float* __restrict__ W2l, const float* __restrict__ W2r,
                          unsigned short* __restrict__ W1lf, unsigned short* __restrict__ W1rf,
                          unsigned short* __restrict__ W2lf, unsigned short* __restrict__ W2rf) {
    int idx = blockIdx.x * blockDim.x + threadIdx.x;   // 0..6143
    const float* W; unsigned short* out; int K; int local;
    if (idx < 1024)      { W = W1l; out = W1lf; K = 64;  local = idx; }
    else if (idx < 2048) { W = W1r; out = W1rf; K = 64;  local = idx - 1024; }
    else if (idx < 4096) { W = W2l; out = W2lf; K = 128; local = idx - 2048; }
    else                 { W = W2r; out = W2rf; K = 128; local = idx - 4096; }
    int l = local & 63;
    int ks = (local >> 6) % (K / 32);
    int nt = (local >> 6) / (K / 32);
    int krow = ks * 32 + (l >> 4) * 8;
    int col = nt * 16 + (l & 15);
    ushort8 o;
#pragma unroll
    for (int j = 0; j < 8; j++) o[j] = f2bf(W[(size_t)(krow + j) * 128 + col]);
    ((ushort8*)out)[local] = o;
}

// ---------------- gather-mean over in-edges, vectorized for MLP ----------------
template <int C>
__global__ __launch_bounds__(256) void k_gatherv(const unsigned short* __restrict__ feat,
                                                 const int* __restrict__ eidx,
                                                 const int* __restrict__ rowstart,
                                                 unsigned short* __restrict__ msg) {
    constexpr int G = C / 8;          // lanes per row: 8 (C=64) or 16 (C=128)
    constexpr int EPW = 64 / G;       // edges in flight: 8 or 4
    const int node = blockIdx.x * 4 + (threadIdx.x >> 6);
    if (node >= NN) return;
    const int lane = threadIdx.x & 63;
    const int grp = lane / G;
    const int sub = lane % G;
    const int lo = rowstart[node];
    const int hi = rowstart[node + 1];

    float acc[8] = {0.f, 0.f, 0.f, 0.f, 0.f, 0.f, 0.f, 0.f};
    int e = lo + grp;
    for (; e + EPW < hi; e += 2 * EPW) {
        int s0 = eidx[e];
        int s1 = eidx[e + EPW];
        ushort8 v0 = *(const ushort8*)&feat[(size_t)s0 * C + sub * 8];
        ushort8 v1 = *(const ushort8*)&feat[(size_t)s1 * C + sub * 8];
#pragma unroll
        for (int j = 0; j < 8; j++) acc[j] += bf2f(v0[j]) + bf2f(v1[j]);
    }
    if (e < hi) {
        int s0 = eidx[e];
        ushort8 v0 = *(const ushort8*)&feat[(size_t)s0 * C + sub * 8];
#pragma unroll
        for (int j = 0; j < 8; j++) acc[j] += bf2f(v0[j]);
    }

#pragma unroll
    for (int off = G; off < 64; off <<= 1) {
#pragma unroll
        for (int j = 0; j < 8; j++) acc[j] += __shfl_xor(acc[j], off, 64);
    }

    if (grp == 0) {
        const float inv = 1.0f / fmaxf((float)(hi - lo), 1.0f);
        ushort8 o;
#pragma unroll
        for (int j = 0; j < 8; j++) o[j] = f2bf(acc[j] * inv);
        *(ushort8*)&msg[(size_t)node * C + sub * 8] = o;
    }
}

// ---------------- fused SAGE layer via MFMA: out = relu(A1@B1 + A2@B2 + bias) ----------------
template <int K>
__global__ __launch_bounds__(256) void k_sage_mfma(const unsigned short* __restrict__ A1,
                                                   const unsigned short* __restrict__ A2,
                                                   const unsigned short* __restrict__ B1,
                                                   const unsigned short* __restrict__ B2,
                                                   const float* __restrict__ bias,
                                                   unsigned short* __restrict__ out) {
    constexpr int KS = K / 32;
    const int wid = threadIdx.x >> 6;
    const int lane = threadIdx.x & 63;
    const int rowbase = blockIdx.x * 64 + wid * 16;
    const int arow = rowbase + (lane & 15);
    const int arowc = (arow < NN) ? arow : (NN - 1);
    const int kgrp = (lane >> 4) * 8;

    f32x4 acc[8];
#pragma unroll
    for (int nt = 0; nt < 8; nt++) {
        float bj = bias[nt * 16 + (lane & 15)];
        acc[nt][0] = bj; acc[nt][1] = bj; acc[nt][2] = bj; acc[nt][3] = bj;
    }

    const bf16x8* b1v = (const bf16x8*)B1;
    const bf16x8* b2v = (const bf16x8*)B2;
#pragma unroll
    for (int ks = 0; ks < KS; ks++) {
        bf16x8 a1 = *(const bf16x8*)&A1[(size_t)arowc * K + ks * 32 + kgrp];
        bf16x8 a2 = *(const bf16x8*)&A2[(size_t)arowc * K + ks * 32 + kgrp];
#pragma unroll
        for (int nt = 0; nt < 8; nt++) {
            acc[nt] = __builtin_amdgcn_mfma_f32_16x16x32_bf16(a1, b1v[(nt * KS + ks) * 64 + lane], acc[nt], 0, 0, 0);
            acc[nt] = __builtin_amdgcn_mfma_f32_16x16x32_bf16(a2, b2v[(nt * KS + ks) * 64 + lane], acc[nt], 0, 0, 0);
        }
    }

    const int colb = lane & 15;
    const int rhi = (lane >> 4) * 4;
#pragma unroll
    for (int nt = 0; nt < 8; nt++) {
#pragma unroll
        for (int r = 0; r < 4; r++) {
            int row = rowbase + rhi + r;
            if (row < NN)
                out[(size_t)row * 128 + nt * 16 + colb] = f2bf(fmaxf(acc[nt][r], 0.0f));
        }
    }
}

// ---------------- fused global-mean-pool + head (bf16 h, fp32 math) ----------------
__device__ __forceinline__ int lower_bound_dev(const int* __restrict__ a, int n, int key) {
    int lo = 0, hi = n;
    while (lo < hi) {
        int mid = (lo + hi) >> 1;
        if (a[mid] < key) lo = mid + 1; else hi = mid;
    }
    return lo;
}

__global__ __launch_bounds__(128) void k_poolb(const unsigned short* __restrict__ h,
                                               const int* __restrict__ batch,
                                               const float* __restrict__ Wh, const float* __restrict__ bh,
                                               float* __restrict__ out) {
    const int g = blockIdx.x;
    const int lo = lower_bound_dev(batch, NN, g);
    const int hi = lower_bound_dev(batch, NN, g + 1);
    const int j = threadIdx.x;
    float s = 0.f;
    for (int i = lo; i < hi; i++) s += bf2f(h[(size_t)i * CH + j]);
    __shared__ float pooled[CH];
    pooled[j] = s / fmaxf((float)(hi - lo), 1.0f);
    __syncthreads();
    if (j < NCLS) {
        float acc = bh[j];
#pragma unroll
        for (int k = 0; k < CH; k++) acc = fmaf(pooled[k], Wh[k * NCLS + j], acc);
        out[(size_t)g * NCLS + j] = acc;
    }
}

extern "C" void kernel_launch(void* const* d_in, const int* in_sizes, int n_in,
                              void* d_out, int out_size, void* d_ws, size_t ws_size,
                              hipStream_t stream) {
    const float* x   = (const float*)d_in[0];
    const void* edge = d_in[1];
    const void* batch= d_in[2];
    const float* W1l = (const float*)d_in[3];
    const float* W1r = (const float*)d_in[4];
    const float* b1  = (const float*)d_in[5];
    const float* W2l = (const float*)d_in[6];
    const float* W2r = (const float*)d_in[7];
    const float* b2  = (const float*)d_in[8];
    const float* Wh  = (const float*)d_in[9];
    const float* bh  = (const float*)d_in[10];
    float* out = (float*)d_out;

    char* p = (char*)d_ws;
    unsigned short* xb   = (unsigned short*)p; p += (size_t)NN * CIN * 2;   // 12.8 MB
    unsigned short* h1b  = (unsigned short*)p; p += (size_t)NN * CH * 2;    // 25.6 MB
    unsigned short* h2b  = (unsigned short*)p; p += (size_t)NN * CH * 2;    // 25.6 MB
    unsigned short* msgb = (unsigned short*)p; p += (size_t)NN * CH * 2;    // 25.6 MB
    unsigned short* W1lf = (unsigned short*)p; p += (size_t)CIN * CH * 2;
    unsigned short* W1rf = (unsigned short*)p; p += (size_t)CIN * CH * 2;
    unsigned short* W2lf = (unsigned short*)p; p += (size_t)CH * CH * 2;
    unsigned short* W2rf = (unsigned short*)p; p += (size_t)CH * CH * 2;
    int* bati  = (int*)p;       p += (size_t)NN * sizeof(int);
    // deg and pv contiguous: one memset covers both
    int* deg   = (int*)p;       p += (size_t)NN * sizeof(int);              // 400000 B (8-aligned)
    unsigned long long* pv = (unsigned long long*)p; p += (size_t)NBLK * 8;
    int* rowstart = (int*)p;    p += (size_t)(NN + 1) * sizeof(int);
    int* cursor   = (int*)p;    p += (size_t)(NN + 1) * sizeof(int) + 4;    // keep 8B align
    int2* ed   = (int2*)p;      p += (size_t)NE * sizeof(int2);             // 12.8 MB (16B-aligned)
    int* eidx  = (int*)p;       p += (size_t)NE * sizeof(int);              // 6.4 MB

    hipMemsetAsync(deg, 0, NN * sizeof(int) + NBLK * 8, stream);
    k_cvt<<<2048, 256, 0, stream>>>(edge, batch, ed, deg, bati);
    k_scan_all<<<NBLK, SCAN_B, 0, stream>>>(deg, pv, rowstart, cursor);
    k_fillx<<<NPART * FILL_BPP, 256, 0, stream>>>(ed, cursor, eidx);

    // conversions (independent of CSR build)
    k_cvtx<<<(NN * CIN / 8 + 255) / 256, 256, 0, stream>>>(x, xb, NN * CIN / 8);
    k_cvtWall<<<24, 256, 0, stream>>>(W1l, W1r, W2l, W2r, W1lf, W1rf, W2lf, W2rf);

    // layer 1
    k_gatherv<CIN><<<(NN + 3) / 4, 256, 0, stream>>>(xb, eidx, rowstart, msgb);
    k_sage_mfma<CIN><<<(NN + 63) / 64, 256, 0, stream>>>(msgb, xb, W1lf, W1rf, b1, h1b);

    // layer 2
    k_gatherv<CH><<<(NN + 3) / 4, 256, 0, stream>>>(h1b, eidx, rowstart, msgb);
    k_sage_mfma<CH><<<(NN + 63) / 64, 256, 0, stream>>>(msgb, h1b, W2lf, W2rf, b2, h2b);

    k_poolb<<<NG, 128, 0, stream>>>(h2b, bati, Wh, bh, out);
}